// Round 4
// baseline (6993.475 us; speedup 1.0000x reference)
//
#include <hip/hip_runtime.h>

#define NUM_USERS 100000
#define NUM_ITEMS 50000
#define NN (NUM_USERS + NUM_ITEMS)
#define EMB_DIM 64
#define BATCH 16384
#define RPB 128                      // rows per bucket (2^7)
#define NB ((NN + RPB - 1) / RPB)    // 1172 buckets
#define LSTRIDE 68                   // LDS row stride in floats (64 + 4 pad)

// init: emb = acc = concat(user_emb, item_emb)
__global__ void lgcn_init(const float4* __restrict__ user_emb,
                          const float4* __restrict__ item_emb,
                          float4* __restrict__ emb, float4* __restrict__ acc,
                          int n_user4, int n_tot4) {
    int i = blockIdx.x * blockDim.x + threadIdx.x;
    if (i >= n_tot4) return;
    float4 v = (i < n_user4) ? user_emb[i] : item_emb[i - n_user4];
    emb[i] = v;
    acc[i] = v;
}

// bucket histogram (1172 counters — L2-resident, low contention)
__global__ void lgcn_bhist(const int* __restrict__ rows, int* __restrict__ bdeg, int nnz) {
    int e = blockIdx.x * blockDim.x + threadIdx.x;
    if (e >= nnz) return;
    atomicAdd(&bdeg[rows[e] >> 7], 1);
}

// single-block exclusive scan over NB buckets -> bptr, cursor
__global__ void lgcn_bscan(const int* __restrict__ bdeg, int* __restrict__ bptr,
                           int* __restrict__ cursor, int nb, int nnz) {
    __shared__ int lds[2048];
    int t = threadIdx.x;
    for (int i = t; i < nb; i += 256) lds[i] = bdeg[i];
    __syncthreads();
    if (t == 0) {
        int run = 0;
        for (int i = 0; i < nb; ++i) { int x = lds[i]; lds[i] = run; run += x; }
    }
    __syncthreads();
    for (int i = t; i < nb; i += 256) { bptr[i] = lds[i]; cursor[i] = lds[i]; }
    if (t == 0) bptr[nb] = nnz;
}

// bin edges into buckets: packed {row_local<<18 | col, val_bits}.
// Positions within a bucket are claimed monotonically -> dense, near-single
// writeback per 64B line (vs 8x for exact-CSR fill).
__global__ void lgcn_bin(const int* __restrict__ rows, const int* __restrict__ cols,
                         const float* __restrict__ vals, int* __restrict__ cursor,
                         int2* __restrict__ cv, int nnz) {
    int e = blockIdx.x * blockDim.x + threadIdx.x;
    if (e >= nnz) return;
    int r = rows[e];
    int p = atomicAdd(&cursor[r >> 7], 1);
    cv[p] = make_int2(((r & (RPB - 1)) << 18) | cols[e], __float_as_int(vals[e]));
}

// SpMM: one workgroup per bucket. LDS accumulator 128 rows x 68 floats.
// 4 waves x (4 edge-groups x 16 dim-lanes); gather emb[col] as float4,
// accumulate into LDS with native fp32 LDS atomics. Dense writeout, acc fused.
__global__ void __launch_bounds__(256) lgcn_spmm(
        const int* __restrict__ bptr,
        const int2* __restrict__ cv,
        const float4* __restrict__ emb4,
        float4* __restrict__ nxt4,
        float4* __restrict__ acc4) {
    __shared__ float lds[RPB * LSTRIDE];   // 34816 B
    int b = blockIdx.x;
    int s = bptr[b];
    int e = bptr[b + 1];
    int t = threadIdx.x;
    for (int i = t; i < RPB * LSTRIDE; i += 256) lds[i] = 0.0f;
    __syncthreads();

    int wave = t >> 6;
    int lane = t & 63;
    int grp  = lane >> 4;    // 0..3 edge group
    int dim4 = lane & 15;    // float4 slice of the 64-dim row

    for (int e0 = s + wave * 64; e0 < e; e0 += 256) {
        int n = e - e0;
        if (n > 64) n = 64;
        int packed = 0; float v = 0.0f;
        if (lane < n) {
            int2 p = cv[e0 + lane];
            packed = p.x; v = __int_as_float(p.y);
        }
        for (int j = 0; j < n; j += 4) {
            int idx = j + grp;
            int pk   = __shfl(packed, idx);
            float vv = __shfl(v, idx);
            if (idx < n) {
                int col = pk & 0x3FFFF;
                int rl  = pk >> 18;
                float4 sv = emb4[(long long)col * 16 + dim4];
                float* dst = &lds[rl * LSTRIDE + dim4 * 4];
                atomicAdd(dst + 0, vv * sv.x);
                atomicAdd(dst + 1, vv * sv.y);
                atomicAdd(dst + 2, vv * sv.z);
                atomicAdd(dst + 3, vv * sv.w);
            }
        }
    }
    __syncthreads();

    // writeout: 128 rows x 16 float4
    int r0 = b * RPB;
    for (int i = t; i < RPB * 16; i += 256) {
        int rl = i >> 4, d4 = i & 15;
        int r = r0 + rl;
        if (r < NN) {
            float4 val = *(const float4*)&lds[rl * LSTRIDE + d4 * 4];
            long long o = (long long)r * 16 + d4;
            float4 av = acc4[o];
            nxt4[o] = val;
            av.x += val.x; av.y += val.y; av.z += val.z; av.w += val.w;
            acc4[o] = av;
        }
    }
}

// out[b] = dot(acc[u], acc[NUM_USERS+i]) / 16 ; 16 lanes per output
__global__ void lgcn_dot(const float* __restrict__ acc,
                         const int* __restrict__ user_idx,
                         const int* __restrict__ item_idx,
                         float* __restrict__ out, int batch) {
    int t = blockIdx.x * blockDim.x + threadIdx.x;
    int b = t >> 4;
    if (b >= batch) return;
    int l = t & 15;
    int u = user_idx[b];
    int it = item_idx[b];
    const float4* ue = (const float4*)(acc + (long long)u * EMB_DIM);
    const float4* ie = (const float4*)(acc + (long long)(NUM_USERS + it) * EMB_DIM);
    float4 a = ue[l], c = ie[l];
    float s = a.x * c.x + a.y * c.y + a.z * c.z + a.w * c.w;
    s += __shfl_down(s, 8, 16);
    s += __shfl_down(s, 4, 16);
    s += __shfl_down(s, 2, 16);
    s += __shfl_down(s, 1, 16);
    if (l == 0) out[b] = s * (1.0f / 16.0f);
}

extern "C" void kernel_launch(void* const* d_in, const int* in_sizes, int n_in,
                              void* d_out, int out_size, void* d_ws, size_t ws_size,
                              hipStream_t stream) {
    const float* user_emb = (const float*)d_in[0];
    const float* item_emb = (const float*)d_in[1];
    const int*   rows     = (const int*)d_in[2];
    const int*   cols     = (const int*)d_in[3];
    const float* vals     = (const float*)d_in[4];
    const int*   user_idx = (const int*)d_in[5];
    const int*   item_idx = (const int*)d_in[6];
    float* out = (float*)d_out;

    const int nnz = in_sizes[2];
    const size_t node_floats = (size_t)NN * EMB_DIM;   // 9.6M

    // workspace layout
    float* emb    = (float*)d_ws;
    float* nxt    = emb + node_floats;
    float* acc    = nxt + node_floats;
    int2*  cv     = (int2*)(acc + node_floats);        // nnz entries (8B)
    int*   bdeg   = (int*)(cv + nnz);
    int*   bptr   = bdeg + NB;                         // NB+1
    int*   cursor = bptr + NB + 1;

    const int n_tot4  = NN * EMB_DIM / 4;
    const int n_user4 = NUM_USERS * EMB_DIM / 4;

    lgcn_init<<<(n_tot4 + 255) / 256, 256, 0, stream>>>(
        (const float4*)user_emb, (const float4*)item_emb,
        (float4*)emb, (float4*)acc, n_user4, n_tot4);

    hipMemsetAsync(bdeg, 0, NB * sizeof(int), stream);
    lgcn_bhist<<<(nnz + 255) / 256, 256, 0, stream>>>(rows, bdeg, nnz);
    lgcn_bscan<<<1, 256, 0, stream>>>(bdeg, bptr, cursor, NB, nnz);
    lgcn_bin<<<(nnz + 255) / 256, 256, 0, stream>>>(rows, cols, vals, cursor, cv, nnz);

    for (int layer = 0; layer < 3; ++layer) {
        lgcn_spmm<<<NB, 256, 0, stream>>>(bptr, cv,
                                          (const float4*)emb,
                                          (float4*)nxt, (float4*)acc);
        float* tmp = emb; emb = nxt; nxt = tmp;
    }

    lgcn_dot<<<(BATCH * 16 + 255) / 256, 256, 0, stream>>>(
        acc, user_idx, item_idx, out, BATCH);
}

// Round 5
// 1170.938 us; speedup vs baseline: 5.9725x; 5.9725x over previous
//
#include <hip/hip_runtime.h>

#define NUM_USERS 100000
#define NUM_ITEMS 50000
#define NN (NUM_USERS + NUM_ITEMS)
#define EMB_DIM 64
#define BATCH 16384
#define SCAN_CHUNK 2048   // elements per scan1 block (256 thr x 8)

// init: emb = acc = concat(user_emb, item_emb)
__global__ void lgcn_init(const float4* __restrict__ user_emb,
                          const float4* __restrict__ item_emb,
                          float4* __restrict__ emb, float4* __restrict__ acc,
                          int n_user4, int n_tot4) {
    int i = blockIdx.x * blockDim.x + threadIdx.x;
    if (i >= n_tot4) return;
    float4 v = (i < n_user4) ? user_emb[i] : item_emb[i - n_user4];
    emb[i] = v;
    acc[i] = v;
}

// ---- CSR build (exact per-row; 150K cursors -> ~32 atomics each, low contention) ----
__global__ void lgcn_hist(const int* __restrict__ rows, int* __restrict__ deg, int nnz) {
    int e = blockIdx.x * blockDim.x + threadIdx.x;
    if (e >= nnz) return;
    atomicAdd(&deg[rows[e]], 1);
}

// per-block exclusive scan (2048 elems/block), emits block totals
__global__ void lgcn_scan1(const int* __restrict__ in, int* __restrict__ out,
                           int* __restrict__ blockSums, int n) {
    __shared__ int lds[256];
    int t = threadIdx.x;
    int base = blockIdx.x * SCAN_CHUNK + t * 8;
    int v[8]; int s = 0;
#pragma unroll
    for (int k = 0; k < 8; ++k) {
        int idx = base + k;
        v[k] = (idx < n) ? in[idx] : 0;
        s += v[k];
    }
    lds[t] = s;
    __syncthreads();
    for (int off = 1; off < 256; off <<= 1) {
        int x = (t >= off) ? lds[t - off] : 0;
        __syncthreads();
        lds[t] += x;
        __syncthreads();
    }
    int run = (t == 0) ? 0 : lds[t - 1];
    if (t == 255) blockSums[blockIdx.x] = lds[255];
#pragma unroll
    for (int k = 0; k < 8; ++k) {
        int idx = base + k;
        if (idx < n) out[idx] = run;
        run += v[k];
    }
}

// exclusive scan of block sums (nb small), single block
__global__ void lgcn_scan2(int* __restrict__ blockSums, int nb) {
    __shared__ int lds[2048];
    int t = threadIdx.x;
    for (int i = t; i < nb; i += 256) lds[i] = blockSums[i];
    __syncthreads();
    if (t == 0) {
        int run = 0;
        for (int i = 0; i < nb; ++i) { int x = lds[i]; lds[i] = run; run += x; }
    }
    __syncthreads();
    for (int i = t; i < nb; i += 256) blockSums[i] = lds[i];
}

// add block offsets; also seed cursor and write row_ptr[n] = nnz
__global__ void lgcn_scan3(int* __restrict__ row_ptr, const int* __restrict__ blockSums,
                           int* __restrict__ cursor, int n, int nnz) {
    int i = blockIdx.x * blockDim.x + threadIdx.x;
    if (i == 0) row_ptr[n] = nnz;
    if (i >= n) return;
    int v = row_ptr[i] + blockSums[i / SCAN_CHUNK];
    row_ptr[i] = v;
    cursor[i] = v;
}

// fill CSR with packed {col, val_bits} — one 8B random store per edge
__global__ void lgcn_fill(const int* __restrict__ rows, const int* __restrict__ cols,
                          const float* __restrict__ vals, int* __restrict__ cursor,
                          int2* __restrict__ cv, int nnz) {
    int e = blockIdx.x * blockDim.x + threadIdx.x;
    if (e >= nnz) return;
    int r = rows[e];
    int p = atomicAdd(&cursor[r], 1);
    cv[p] = make_int2(cols[e], __float_as_int(vals[e]));
}

// ---- gather SpMM: one wave per row; 4 groups x 16 dim-lanes.
// Group g owns edge sub-stream {start + g + 4k}. k-loop unrolled x4 so
// 4 independent 256B gathers are in flight per wave (MLP fix).
// nxt[r] = sum_e val*emb[col]; acc[r] += nxt[r]  (fused)
__global__ void __launch_bounds__(256) lgcn_spmm(
        const int* __restrict__ row_ptr,
        const int2* __restrict__ cv,
        const float4* __restrict__ emb4,
        float4* __restrict__ nxt4,
        float4* __restrict__ acc4) {
    int wid = (blockIdx.x * blockDim.x + threadIdx.x) >> 6;
    int lane = threadIdx.x & 63;
    if (wid >= NN) return;
    int start = row_ptr[wid];
    int n = row_ptr[wid + 1] - start;
    int grp  = lane >> 4;    // 0..3 edge group
    int dim4 = lane & 15;    // float4 slice of the 64-dim row
    const int2* ep = cv + start;

    float4 a = {0.f, 0.f, 0.f, 0.f};
    int m = n >> 2;          // rounds where all 4 groups have an edge
    int k = 0;
    for (; k + 4 <= m; k += 4) {
        int2 p0 = ep[4 * k      + grp];
        int2 p1 = ep[4 * k + 4  + grp];
        int2 p2 = ep[4 * k + 8  + grp];
        int2 p3 = ep[4 * k + 12 + grp];
        float4 s0 = emb4[(long long)p0.x * 16 + dim4];
        float4 s1 = emb4[(long long)p1.x * 16 + dim4];
        float4 s2 = emb4[(long long)p2.x * 16 + dim4];
        float4 s3 = emb4[(long long)p3.x * 16 + dim4];
        float v0 = __int_as_float(p0.y), v1 = __int_as_float(p1.y);
        float v2 = __int_as_float(p2.y), v3 = __int_as_float(p3.y);
        a.x += v0 * s0.x; a.y += v0 * s0.y; a.z += v0 * s0.z; a.w += v0 * s0.w;
        a.x += v1 * s1.x; a.y += v1 * s1.y; a.z += v1 * s1.z; a.w += v1 * s1.w;
        a.x += v2 * s2.x; a.y += v2 * s2.y; a.z += v2 * s2.z; a.w += v2 * s2.w;
        a.x += v3 * s3.x; a.y += v3 * s3.y; a.z += v3 * s3.z; a.w += v3 * s3.w;
    }
    for (; k < m; ++k) {
        int2 p = ep[4 * k + grp];
        float4 s = emb4[(long long)p.x * 16 + dim4];
        float v = __int_as_float(p.y);
        a.x += v * s.x; a.y += v * s.y; a.z += v * s.z; a.w += v * s.w;
    }
    int rem = n & 3;
    if (grp < rem) {
        int2 p = ep[4 * m + grp];
        float4 s = emb4[(long long)p.x * 16 + dim4];
        float v = __int_as_float(p.y);
        a.x += v * s.x; a.y += v * s.y; a.z += v * s.z; a.w += v * s.w;
    }

    // reduce the 4 edge-groups onto group 0
    a.x += __shfl_xor(a.x, 16); a.y += __shfl_xor(a.y, 16);
    a.z += __shfl_xor(a.z, 16); a.w += __shfl_xor(a.w, 16);
    a.x += __shfl_xor(a.x, 32); a.y += __shfl_xor(a.y, 32);
    a.z += __shfl_xor(a.z, 32); a.w += __shfl_xor(a.w, 32);
    if (grp == 0) {
        long long o = (long long)wid * 16 + dim4;
        float4 av = acc4[o];
        nxt4[o] = a;
        av.x += a.x; av.y += a.y; av.z += a.z; av.w += a.w;
        acc4[o] = av;
    }
}

// out[b] = dot(acc[u], acc[NUM_USERS+i]) / 16 ; 16 lanes per output
__global__ void lgcn_dot(const float* __restrict__ acc,
                         const int* __restrict__ user_idx,
                         const int* __restrict__ item_idx,
                         float* __restrict__ out, int batch) {
    int t = blockIdx.x * blockDim.x + threadIdx.x;
    int b = t >> 4;
    if (b >= batch) return;
    int l = t & 15;
    int u = user_idx[b];
    int it = item_idx[b];
    const float4* ue = (const float4*)(acc + (long long)u * EMB_DIM);
    const float4* ie = (const float4*)(acc + (long long)(NUM_USERS + it) * EMB_DIM);
    float4 a = ue[l], c = ie[l];
    float s = a.x * c.x + a.y * c.y + a.z * c.z + a.w * c.w;
    s += __shfl_down(s, 8, 16);
    s += __shfl_down(s, 4, 16);
    s += __shfl_down(s, 2, 16);
    s += __shfl_down(s, 1, 16);
    if (l == 0) out[b] = s * (1.0f / 16.0f);
}

extern "C" void kernel_launch(void* const* d_in, const int* in_sizes, int n_in,
                              void* d_out, int out_size, void* d_ws, size_t ws_size,
                              hipStream_t stream) {
    const float* user_emb = (const float*)d_in[0];
    const float* item_emb = (const float*)d_in[1];
    const int*   rows     = (const int*)d_in[2];
    const int*   cols     = (const int*)d_in[3];
    const float* vals     = (const float*)d_in[4];
    const int*   user_idx = (const int*)d_in[5];
    const int*   item_idx = (const int*)d_in[6];
    float* out = (float*)d_out;

    const int nnz = in_sizes[2];
    const size_t node_floats = (size_t)NN * EMB_DIM;   // 9.6M

    // workspace layout
    float* emb     = (float*)d_ws;
    float* nxt     = emb + node_floats;
    float* acc     = nxt + node_floats;
    int2*  cv      = (int2*)(acc + node_floats);       // nnz entries (8B)
    int*   deg     = (int*)(cv + nnz);
    int*   row_ptr = deg + NN;                         // NN+1 entries
    int*   cursor  = row_ptr + NN + 1;
    int*   bsums   = cursor + NN;

    const int n_tot4  = NN * EMB_DIM / 4;
    const int n_user4 = NUM_USERS * EMB_DIM / 4;

    lgcn_init<<<(n_tot4 + 255) / 256, 256, 0, stream>>>(
        (const float4*)user_emb, (const float4*)item_emb,
        (float4*)emb, (float4*)acc, n_user4, n_tot4);

    // CSR build
    hipMemsetAsync(deg, 0, NN * sizeof(int), stream);
    lgcn_hist<<<(nnz + 255) / 256, 256, 0, stream>>>(rows, deg, nnz);
    const int nScanBlocks = (NN + SCAN_CHUNK - 1) / SCAN_CHUNK;   // 74
    lgcn_scan1<<<nScanBlocks, 256, 0, stream>>>(deg, row_ptr, bsums, NN);
    lgcn_scan2<<<1, 256, 0, stream>>>(bsums, nScanBlocks);
    lgcn_scan3<<<(NN + 255) / 256, 256, 0, stream>>>(row_ptr, bsums, cursor, NN, nnz);
    lgcn_fill<<<(nnz + 255) / 256, 256, 0, stream>>>(rows, cols, vals, cursor, cv, nnz);

    // 3 layers of gather SpMM (ping-pong emb/nxt), acc fused
    const int spmm_blocks = (NN * 64 + 255) / 256;   // one wave per row
    for (int layer = 0; layer < 3; ++layer) {
        lgcn_spmm<<<spmm_blocks, 256, 0, stream>>>(row_ptr, cv,
                                                   (const float4*)emb,
                                                   (float4*)nxt, (float4*)acc);
        float* tmp = emb; emb = nxt; nxt = tmp;
    }

    lgcn_dot<<<(BATCH * 16 + 255) / 256, 256, 0, stream>>>(
        acc, user_idx, item_idx, out, BATCH);
}

// Round 6
// 1087.161 us; speedup vs baseline: 6.4328x; 1.0771x over previous
//
#include <hip/hip_runtime.h>

#define NUM_USERS 100000
#define NUM_ITEMS 50000
#define NN (NUM_USERS + NUM_ITEMS)
#define EMB_DIM 64
#define BATCH 16384
#define SCAN_CHUNK 2048   // elements per scan1 block (256 thr x 8)
#define RPB 128                       // rows per coarse bucket
#define NBKT ((NN + RPB - 1) / RPB)   // 1172 buckets
#define EPB 16384                     // edges per binA block

// init: emb = acc = concat(user_emb, item_emb)
__global__ void lgcn_init(const float4* __restrict__ user_emb,
                          const float4* __restrict__ item_emb,
                          float4* __restrict__ emb, float4* __restrict__ acc,
                          int n_user4, int n_tot4) {
    int i = blockIdx.x * blockDim.x + threadIdx.x;
    if (i >= n_tot4) return;
    float4 v = (i < n_user4) ? user_emb[i] : item_emb[i - n_user4];
    emb[i] = v;
    acc[i] = v;
}

// per-row degree histogram (150K counters, ~32 hits each: low contention)
__global__ void lgcn_hist(const int* __restrict__ rows, int* __restrict__ deg, int nnz) {
    int e = blockIdx.x * blockDim.x + threadIdx.x;
    if (e >= nnz) return;
    atomicAdd(&deg[rows[e]], 1);
}

// per-block exclusive scan (2048 elems/block), emits block totals
__global__ void lgcn_scan1(const int* __restrict__ in, int* __restrict__ out,
                           int* __restrict__ blockSums, int n) {
    __shared__ int lds[256];
    int t = threadIdx.x;
    int base = blockIdx.x * SCAN_CHUNK + t * 8;
    int v[8]; int s = 0;
#pragma unroll
    for (int k = 0; k < 8; ++k) {
        int idx = base + k;
        v[k] = (idx < n) ? in[idx] : 0;
        s += v[k];
    }
    lds[t] = s;
    __syncthreads();
    for (int off = 1; off < 256; off <<= 1) {
        int x = (t >= off) ? lds[t - off] : 0;
        __syncthreads();
        lds[t] += x;
        __syncthreads();
    }
    int run = (t == 0) ? 0 : lds[t - 1];
    if (t == 255) blockSums[blockIdx.x] = lds[255];
#pragma unroll
    for (int k = 0; k < 8; ++k) {
        int idx = base + k;
        if (idx < n) out[idx] = run;
        run += v[k];
    }
}

// exclusive scan of block sums (nb small), single block
__global__ void lgcn_scan2(int* __restrict__ blockSums, int nb) {
    __shared__ int lds[2048];
    int t = threadIdx.x;
    for (int i = t; i < nb; i += 256) lds[i] = blockSums[i];
    __syncthreads();
    if (t == 0) {
        int run = 0;
        for (int i = 0; i < nb; ++i) { int x = lds[i]; lds[i] = run; run += x; }
    }
    __syncthreads();
    for (int i = t; i < nb; i += 256) blockSums[i] = lds[i];
}

// add block offsets -> row_ptr; seed per-bucket cursor gcur[b]=row_ptr[b*128]
__global__ void lgcn_scan3(int* __restrict__ row_ptr, const int* __restrict__ blockSums,
                           int* __restrict__ gcur, int n, int nnz) {
    int i = blockIdx.x * blockDim.x + threadIdx.x;
    if (i == 0) row_ptr[n] = nnz;
    if (i >= n) return;
    int v = row_ptr[i] + blockSums[i / SCAN_CHUNK];
    row_ptr[i] = v;
    if ((i & (RPB - 1)) == 0) gcur[i >> 7] = v;
}

// binA: coarse bucket scatter with block-aggregated claims.
// Each block: LDS hist over 1172 buckets, ONE global atomicAdd per
// (block,bucket) to claim a contiguous run, then scatter via LDS cursors.
// Writes land in runs of ~EPB/NBKT consecutive edges -> line-local.
// Packs {row_local<<18 | col, val_bits}.
__global__ void __launch_bounds__(256) lgcn_binA(
        const int* __restrict__ rows, const int* __restrict__ cols,
        const float* __restrict__ vals, int* __restrict__ gcur,
        int2* __restrict__ cv_tmp, int nnz) {
    __shared__ int hist[NBKT];
    __shared__ int cur[NBKT];
    int t = threadIdx.x;
    int base = blockIdx.x * EPB;
    for (int i = t; i < NBKT; i += 256) hist[i] = 0;
    __syncthreads();
    for (int i = base + t; i < base + EPB && i < nnz; i += 256)
        atomicAdd(&hist[rows[i] >> 7], 1);
    __syncthreads();
    for (int b = t; b < NBKT; b += 256) {
        int c = hist[b];
        cur[b] = c ? atomicAdd(&gcur[b], c) : 0;
    }
    __syncthreads();
    for (int i = base + t; i < base + EPB && i < nnz; i += 256) {
        int r = rows[i];
        int p = atomicAdd(&cur[r >> 7], 1);
        cv_tmp[p] = make_int2(((r & (RPB - 1)) << 18) | cols[i],
                              __float_as_int(vals[i]));
    }
}

// binB: one workgroup per bucket; LDS row-cursors seeded from row_ptr;
// scatter bucket edges into exact CSR. All writes in the bucket's
// contiguous ~32KB window -> single writeback per line.
__global__ void __launch_bounds__(256) lgcn_binB(
        const int* __restrict__ row_ptr, const int2* __restrict__ cv_tmp,
        int2* __restrict__ cv) {
    __shared__ int cur[RPB];
    int b = blockIdx.x;
    int t = threadIdx.x;
    int r0 = b * RPB;
    int rend = r0 + RPB; if (rend > NN) rend = NN;
    int nrows = rend - r0;
    if (t < nrows) cur[t] = row_ptr[r0 + t];
    int s = row_ptr[r0];
    int e = row_ptr[rend];
    __syncthreads();
    for (int i = s + t; i < e; i += 256) {
        int2 p = cv_tmp[i];
        int rl = ((unsigned)p.x) >> 18;
        int pos = atomicAdd(&cur[rl], 1);
        cv[pos] = make_int2(p.x & 0x3FFFF, p.y);
    }
}

// ---- gather SpMM: one wave per row; 4 groups x 16 dim-lanes.
// Group g owns edge sub-stream {start + g + 4k}; k-loop unrolled x8 so
// 8 independent 256B gathers are in flight per wave.
// nxt[r] = sum_e val*emb[col]; acc[r] += nxt[r]  (fused)
__global__ void __launch_bounds__(256) lgcn_spmm(
        const int* __restrict__ row_ptr,
        const int2* __restrict__ cv,
        const float4* __restrict__ emb4,
        float4* __restrict__ nxt4,
        float4* __restrict__ acc4) {
    int wid = (blockIdx.x * blockDim.x + threadIdx.x) >> 6;
    int lane = threadIdx.x & 63;
    if (wid >= NN) return;
    int start = row_ptr[wid];
    int n = row_ptr[wid + 1] - start;
    int grp  = lane >> 4;    // 0..3 edge group
    int dim4 = lane & 15;    // float4 slice of the 64-dim row
    const int2* ep = cv + start;

    float4 a = {0.f, 0.f, 0.f, 0.f};
    int m = n >> 2;          // rounds where all 4 groups have an edge
    int k = 0;
    for (; k + 8 <= m; k += 8) {
        int2 p0 = ep[4 * k      + grp];
        int2 p1 = ep[4 * k + 4  + grp];
        int2 p2 = ep[4 * k + 8  + grp];
        int2 p3 = ep[4 * k + 12 + grp];
        int2 p4 = ep[4 * k + 16 + grp];
        int2 p5 = ep[4 * k + 20 + grp];
        int2 p6 = ep[4 * k + 24 + grp];
        int2 p7 = ep[4 * k + 28 + grp];
        float4 s0 = emb4[(long long)p0.x * 16 + dim4];
        float4 s1 = emb4[(long long)p1.x * 16 + dim4];
        float4 s2 = emb4[(long long)p2.x * 16 + dim4];
        float4 s3 = emb4[(long long)p3.x * 16 + dim4];
        float4 s4 = emb4[(long long)p4.x * 16 + dim4];
        float4 s5 = emb4[(long long)p5.x * 16 + dim4];
        float4 s6 = emb4[(long long)p6.x * 16 + dim4];
        float4 s7 = emb4[(long long)p7.x * 16 + dim4];
        float v0 = __int_as_float(p0.y), v1 = __int_as_float(p1.y);
        float v2 = __int_as_float(p2.y), v3 = __int_as_float(p3.y);
        float v4 = __int_as_float(p4.y), v5 = __int_as_float(p5.y);
        float v6 = __int_as_float(p6.y), v7 = __int_as_float(p7.y);
        a.x += v0 * s0.x; a.y += v0 * s0.y; a.z += v0 * s0.z; a.w += v0 * s0.w;
        a.x += v1 * s1.x; a.y += v1 * s1.y; a.z += v1 * s1.z; a.w += v1 * s1.w;
        a.x += v2 * s2.x; a.y += v2 * s2.y; a.z += v2 * s2.z; a.w += v2 * s2.w;
        a.x += v3 * s3.x; a.y += v3 * s3.y; a.z += v3 * s3.z; a.w += v3 * s3.w;
        a.x += v4 * s4.x; a.y += v4 * s4.y; a.z += v4 * s4.z; a.w += v4 * s4.w;
        a.x += v5 * s5.x; a.y += v5 * s5.y; a.z += v5 * s5.z; a.w += v5 * s5.w;
        a.x += v6 * s6.x; a.y += v6 * s6.y; a.z += v6 * s6.z; a.w += v6 * s6.w;
        a.x += v7 * s7.x; a.y += v7 * s7.y; a.z += v7 * s7.z; a.w += v7 * s7.w;
    }
    for (; k < m; ++k) {
        int2 p = ep[4 * k + grp];
        float4 s = emb4[(long long)p.x * 16 + dim4];
        float v = __int_as_float(p.y);
        a.x += v * s.x; a.y += v * s.y; a.z += v * s.z; a.w += v * s.w;
    }
    int rem = n & 3;
    if (grp < rem) {
        int2 p = ep[4 * m + grp];
        float4 s = emb4[(long long)p.x * 16 + dim4];
        float v = __int_as_float(p.y);
        a.x += v * s.x; a.y += v * s.y; a.z += v * s.z; a.w += v * s.w;
    }

    // reduce the 4 edge-groups onto group 0
    a.x += __shfl_xor(a.x, 16); a.y += __shfl_xor(a.y, 16);
    a.z += __shfl_xor(a.z, 16); a.w += __shfl_xor(a.w, 16);
    a.x += __shfl_xor(a.x, 32); a.y += __shfl_xor(a.y, 32);
    a.z += __shfl_xor(a.z, 32); a.w += __shfl_xor(a.w, 32);
    if (grp == 0) {
        long long o = (long long)wid * 16 + dim4;
        float4 av = acc4[o];
        nxt4[o] = a;
        av.x += a.x; av.y += a.y; av.z += a.z; av.w += a.w;
        acc4[o] = av;
    }
}

// out[b] = dot(acc[u], acc[NUM_USERS+i]) / 16 ; 16 lanes per output
__global__ void lgcn_dot(const float* __restrict__ acc,
                         const int* __restrict__ user_idx,
                         const int* __restrict__ item_idx,
                         float* __restrict__ out, int batch) {
    int t = blockIdx.x * blockDim.x + threadIdx.x;
    int b = t >> 4;
    if (b >= batch) return;
    int l = t & 15;
    int u = user_idx[b];
    int it = item_idx[b];
    const float4* ue = (const float4*)(acc + (long long)u * EMB_DIM);
    const float4* ie = (const float4*)(acc + (long long)(NUM_USERS + it) * EMB_DIM);
    float4 a = ue[l], c = ie[l];
    float s = a.x * c.x + a.y * c.y + a.z * c.z + a.w * c.w;
    s += __shfl_down(s, 8, 16);
    s += __shfl_down(s, 4, 16);
    s += __shfl_down(s, 2, 16);
    s += __shfl_down(s, 1, 16);
    if (l == 0) out[b] = s * (1.0f / 16.0f);
}

extern "C" void kernel_launch(void* const* d_in, const int* in_sizes, int n_in,
                              void* d_out, int out_size, void* d_ws, size_t ws_size,
                              hipStream_t stream) {
    const float* user_emb = (const float*)d_in[0];
    const float* item_emb = (const float*)d_in[1];
    const int*   rows     = (const int*)d_in[2];
    const int*   cols     = (const int*)d_in[3];
    const float* vals     = (const float*)d_in[4];
    const int*   user_idx = (const int*)d_in[5];
    const int*   item_idx = (const int*)d_in[6];
    float* out = (float*)d_out;

    const int nnz = in_sizes[2];
    const size_t node_floats = (size_t)NN * EMB_DIM;   // 9.6M

    // workspace layout (cv_tmp aliases nxt: binA/binB finish before spmm)
    float* emb     = (float*)d_ws;
    float* nxt     = emb + node_floats;
    float* acc     = nxt + node_floats;
    int2*  cv      = (int2*)(acc + node_floats);       // nnz entries (8B)
    int*   deg     = (int*)(cv + nnz);
    int*   row_ptr = deg + NN;                         // NN+1 entries
    int*   gcur    = row_ptr + NN + 1;                 // NBKT bucket cursors
    int*   bsums   = gcur + NBKT;
    int2*  cv_tmp  = (int2*)nxt;                       // 38.4MB scratch, freed by spmm

    const int n_tot4  = NN * EMB_DIM / 4;
    const int n_user4 = NUM_USERS * EMB_DIM / 4;

    lgcn_init<<<(n_tot4 + 255) / 256, 256, 0, stream>>>(
        (const float4*)user_emb, (const float4*)item_emb,
        (float4*)emb, (float4*)acc, n_user4, n_tot4);

    // row_ptr build
    hipMemsetAsync(deg, 0, NN * sizeof(int), stream);
    lgcn_hist<<<(nnz + 255) / 256, 256, 0, stream>>>(rows, deg, nnz);
    const int nScanBlocks = (NN + SCAN_CHUNK - 1) / SCAN_CHUNK;   // 74
    lgcn_scan1<<<nScanBlocks, 256, 0, stream>>>(deg, row_ptr, bsums, NN);
    lgcn_scan2<<<1, 256, 0, stream>>>(bsums, nScanBlocks);
    lgcn_scan3<<<(NN + 255) / 256, 256, 0, stream>>>(row_ptr, bsums, gcur, NN, nnz);

    // two-level counting sort into exact CSR
    lgcn_binA<<<(nnz + EPB - 1) / EPB, 256, 0, stream>>>(rows, cols, vals, gcur,
                                                         cv_tmp, nnz);
    lgcn_binB<<<NBKT, 256, 0, stream>>>(row_ptr, cv_tmp, cv);

    // 3 layers of gather SpMM (ping-pong emb/nxt), acc fused
    const int spmm_blocks = (NN * 64 + 255) / 256;   // one wave per row
    for (int layer = 0; layer < 3; ++layer) {
        lgcn_spmm<<<spmm_blocks, 256, 0, stream>>>(row_ptr, cv,
                                                   (const float4*)emb,
                                                   (float4*)nxt, (float4*)acc);
        float* tmp = emb; emb = nxt; nxt = tmp;
    }

    lgcn_dot<<<(BATCH * 16 + 255) / 256, 256, 0, stream>>>(
        acc, user_idx, item_idx, out, BATCH);
}

// Round 7
// 901.021 us; speedup vs baseline: 7.7617x; 1.2066x over previous
//
#include <hip/hip_runtime.h>
#include <hip/hip_fp16.h>

#define NUM_USERS 100000
#define NUM_ITEMS 50000
#define NN (NUM_USERS + NUM_ITEMS)
#define EMB_DIM 64
#define BATCH 16384
#define SCAN_CHUNK 2048   // elements per scan1 block (256 thr x 8)
#define RPB 128                       // rows per coarse bucket
#define NBKT ((NN + RPB - 1) / RPB)   // 1172 buckets
#define EPB 16384                     // edges per binA block

// init: acc = concat(user_emb, item_emb) fp32; emb = same, quantized fp16
__global__ void lgcn_init(const float4* __restrict__ user_emb,
                          const float4* __restrict__ item_emb,
                          uint2* __restrict__ embh, float4* __restrict__ acc,
                          int n_user4, int n_tot4) {
    int i = blockIdx.x * blockDim.x + threadIdx.x;
    if (i >= n_tot4) return;
    float4 v = (i < n_user4) ? user_emb[i] : item_emb[i - n_user4];
    acc[i] = v;
    __half2 lo = __float22half2_rn(make_float2(v.x, v.y));
    __half2 hi = __float22half2_rn(make_float2(v.z, v.w));
    uint2 o;
    o.x = *(unsigned int*)&lo;
    o.y = *(unsigned int*)&hi;
    embh[i] = o;
}

// per-row degree histogram (150K counters, ~32 hits each: low contention)
__global__ void lgcn_hist(const int* __restrict__ rows, int* __restrict__ deg, int nnz) {
    int e = blockIdx.x * blockDim.x + threadIdx.x;
    if (e >= nnz) return;
    atomicAdd(&deg[rows[e]], 1);
}

// per-block exclusive scan (2048 elems/block), emits block totals
__global__ void lgcn_scan1(const int* __restrict__ in, int* __restrict__ out,
                           int* __restrict__ blockSums, int n) {
    __shared__ int lds[256];
    int t = threadIdx.x;
    int base = blockIdx.x * SCAN_CHUNK + t * 8;
    int v[8]; int s = 0;
#pragma unroll
    for (int k = 0; k < 8; ++k) {
        int idx = base + k;
        v[k] = (idx < n) ? in[idx] : 0;
        s += v[k];
    }
    lds[t] = s;
    __syncthreads();
    for (int off = 1; off < 256; off <<= 1) {
        int x = (t >= off) ? lds[t - off] : 0;
        __syncthreads();
        lds[t] += x;
        __syncthreads();
    }
    int run = (t == 0) ? 0 : lds[t - 1];
    if (t == 255) blockSums[blockIdx.x] = lds[255];
#pragma unroll
    for (int k = 0; k < 8; ++k) {
        int idx = base + k;
        if (idx < n) out[idx] = run;
        run += v[k];
    }
}

// exclusive scan of block sums (nb small), single block
__global__ void lgcn_scan2(int* __restrict__ blockSums, int nb) {
    __shared__ int lds[2048];
    int t = threadIdx.x;
    for (int i = t; i < nb; i += 256) lds[i] = blockSums[i];
    __syncthreads();
    if (t == 0) {
        int run = 0;
        for (int i = 0; i < nb; ++i) { int x = lds[i]; lds[i] = run; run += x; }
    }
    __syncthreads();
    for (int i = t; i < nb; i += 256) blockSums[i] = lds[i];
}

// add block offsets -> row_ptr; seed per-bucket cursor gcur[b]=row_ptr[b*128]
__global__ void lgcn_scan3(int* __restrict__ row_ptr, const int* __restrict__ blockSums,
                           int* __restrict__ gcur, int n, int nnz) {
    int i = blockIdx.x * blockDim.x + threadIdx.x;
    if (i == 0) row_ptr[n] = nnz;
    if (i >= n) return;
    int v = row_ptr[i] + blockSums[i / SCAN_CHUNK];
    row_ptr[i] = v;
    if ((i & (RPB - 1)) == 0) gcur[i >> 7] = v;
}

// binA: coarse bucket scatter with block-aggregated claims.
__global__ void __launch_bounds__(256) lgcn_binA(
        const int* __restrict__ rows, const int* __restrict__ cols,
        const float* __restrict__ vals, int* __restrict__ gcur,
        int2* __restrict__ cv_tmp, int nnz) {
    __shared__ int hist[NBKT];
    __shared__ int cur[NBKT];
    int t = threadIdx.x;
    int base = blockIdx.x * EPB;
    for (int i = t; i < NBKT; i += 256) hist[i] = 0;
    __syncthreads();
    for (int i = base + t; i < base + EPB && i < nnz; i += 256)
        atomicAdd(&hist[rows[i] >> 7], 1);
    __syncthreads();
    for (int b = t; b < NBKT; b += 256) {
        int c = hist[b];
        cur[b] = c ? atomicAdd(&gcur[b], c) : 0;
    }
    __syncthreads();
    for (int i = base + t; i < base + EPB && i < nnz; i += 256) {
        int r = rows[i];
        int p = atomicAdd(&cur[r >> 7], 1);
        cv_tmp[p] = make_int2(((r & (RPB - 1)) << 18) | cols[i],
                              __float_as_int(vals[i]));
    }
}

// binB: one workgroup per bucket; LDS row-cursors seeded from row_ptr;
// scatter bucket edges into exact CSR (writes stay in a ~32KB window).
__global__ void __launch_bounds__(256) lgcn_binB(
        const int* __restrict__ row_ptr, const int2* __restrict__ cv_tmp,
        int2* __restrict__ cv) {
    __shared__ int cur[RPB];
    int b = blockIdx.x;
    int t = threadIdx.x;
    int r0 = b * RPB;
    int rend = r0 + RPB; if (rend > NN) rend = NN;
    int nrows = rend - r0;
    if (t < nrows) cur[t] = row_ptr[r0 + t];
    int s = row_ptr[r0];
    int e = row_ptr[rend];
    __syncthreads();
    for (int i = s + t; i < e; i += 256) {
        int2 p = cv_tmp[i];
        int rl = ((unsigned)p.x) >> 18;
        int pos = atomicAdd(&cur[rl], 1);
        cv[pos] = make_int2(p.x & 0x3FFFF, p.y);
    }
}

// ---- gather SpMM, fp16 table: one wave per row; 4 groups x 16 dim-lanes.
// Each lane gathers 8B (4 halves) of emb[col]; k-loop unrolled x8 for MLP.
// nxt(fp16)[r] = sum_e val*emb[col]; acc(fp32)[r] += same (fused, fp32 regs)
__global__ void __launch_bounds__(256) lgcn_spmm(
        const int* __restrict__ row_ptr,
        const int2* __restrict__ cv,
        const uint2* __restrict__ embh,
        uint2* __restrict__ nxth,
        float4* __restrict__ acc4) {
    int wid = (blockIdx.x * blockDim.x + threadIdx.x) >> 6;
    int lane = threadIdx.x & 63;
    if (wid >= NN) return;
    int start = row_ptr[wid];
    int n = row_ptr[wid + 1] - start;
    int grp  = lane >> 4;    // 0..3 edge group
    int dim4 = lane & 15;    // 8B (4-half) slice of the 64-dim row
    const int2* ep = cv + start;

    float4 a = {0.f, 0.f, 0.f, 0.f};
    int m = n >> 2;          // rounds where all 4 groups have an edge
    int k = 0;
    for (; k + 8 <= m; k += 8) {
        int2 p[8];
        uint2 raw[8];
#pragma unroll
        for (int j = 0; j < 8; ++j) p[j] = ep[4 * (k + j) + grp];
#pragma unroll
        for (int j = 0; j < 8; ++j)
            raw[j] = embh[(long long)p[j].x * 16 + dim4];
#pragma unroll
        for (int j = 0; j < 8; ++j) {
            float v = __int_as_float(p[j].y);
            __half2* h = (__half2*)&raw[j];
            float2 f0 = __half22float2(h[0]);
            float2 f1 = __half22float2(h[1]);
            a.x += v * f0.x; a.y += v * f0.y;
            a.z += v * f1.x; a.w += v * f1.y;
        }
    }
    for (; k < m; ++k) {
        int2 p = ep[4 * k + grp];
        uint2 raw = embh[(long long)p.x * 16 + dim4];
        float v = __int_as_float(p.y);
        __half2* h = (__half2*)&raw;
        float2 f0 = __half22float2(h[0]);
        float2 f1 = __half22float2(h[1]);
        a.x += v * f0.x; a.y += v * f0.y;
        a.z += v * f1.x; a.w += v * f1.y;
    }
    int rem = n & 3;
    if (grp < rem) {
        int2 p = ep[4 * m + grp];
        uint2 raw = embh[(long long)p.x * 16 + dim4];
        float v = __int_as_float(p.y);
        __half2* h = (__half2*)&raw;
        float2 f0 = __half22float2(h[0]);
        float2 f1 = __half22float2(h[1]);
        a.x += v * f0.x; a.y += v * f0.y;
        a.z += v * f1.x; a.w += v * f1.y;
    }

    // reduce the 4 edge-groups onto group 0
    a.x += __shfl_xor(a.x, 16); a.y += __shfl_xor(a.y, 16);
    a.z += __shfl_xor(a.z, 16); a.w += __shfl_xor(a.w, 16);
    a.x += __shfl_xor(a.x, 32); a.y += __shfl_xor(a.y, 32);
    a.z += __shfl_xor(a.z, 32); a.w += __shfl_xor(a.w, 32);
    if (grp == 0) {
        long long o = (long long)wid * 16 + dim4;
        float4 av = acc4[o];
        __half2 lo = __float22half2_rn(make_float2(a.x, a.y));
        __half2 hi = __float22half2_rn(make_float2(a.z, a.w));
        uint2 ov;
        ov.x = *(unsigned int*)&lo;
        ov.y = *(unsigned int*)&hi;
        nxth[o] = ov;
        av.x += a.x; av.y += a.y; av.z += a.z; av.w += a.w;
        acc4[o] = av;
    }
}

// out[b] = dot(acc[u], acc[NUM_USERS+i]) / 16 ; 16 lanes per output
__global__ void lgcn_dot(const float* __restrict__ acc,
                         const int* __restrict__ user_idx,
                         const int* __restrict__ item_idx,
                         float* __restrict__ out, int batch) {
    int t = blockIdx.x * blockDim.x + threadIdx.x;
    int b = t >> 4;
    if (b >= batch) return;
    int l = t & 15;
    int u = user_idx[b];
    int it = item_idx[b];
    const float4* ue = (const float4*)(acc + (long long)u * EMB_DIM);
    const float4* ie = (const float4*)(acc + (long long)(NUM_USERS + it) * EMB_DIM);
    float4 a = ue[l], c = ie[l];
    float s = a.x * c.x + a.y * c.y + a.z * c.z + a.w * c.w;
    s += __shfl_down(s, 8, 16);
    s += __shfl_down(s, 4, 16);
    s += __shfl_down(s, 2, 16);
    s += __shfl_down(s, 1, 16);
    if (l == 0) out[b] = s * (1.0f / 16.0f);
}

extern "C" void kernel_launch(void* const* d_in, const int* in_sizes, int n_in,
                              void* d_out, int out_size, void* d_ws, size_t ws_size,
                              hipStream_t stream) {
    const float* user_emb = (const float*)d_in[0];
    const float* item_emb = (const float*)d_in[1];
    const int*   rows     = (const int*)d_in[2];
    const int*   cols     = (const int*)d_in[3];
    const float* vals     = (const float*)d_in[4];
    const int*   user_idx = (const int*)d_in[5];
    const int*   item_idx = (const int*)d_in[6];
    float* out = (float*)d_out;

    const int nnz = in_sizes[2];
    const size_t node_floats = (size_t)NN * EMB_DIM;      // 9.6M
    const size_t node_uint2  = node_floats / 4;           // 2.4M (fp16 rows as uint2)

    // workspace layout: acc fp32 (38.4MB) | embA fp16 (19.2) | embB fp16 (19.2)
    //                   | cv (38.4) | cv_tmp (38.4) | small ints
    float* acc     = (float*)d_ws;
    uint2* embA    = (uint2*)(acc + node_floats);
    uint2* embB    = embA + node_uint2;
    int2*  cv      = (int2*)(embB + node_uint2);
    int2*  cv_tmp  = cv + nnz;
    int*   deg     = (int*)(cv_tmp + nnz);
    int*   row_ptr = deg + NN;                            // NN+1 entries
    int*   gcur    = row_ptr + NN + 1;                    // NBKT cursors
    int*   bsums   = gcur + NBKT;

    const int n_tot4  = NN * EMB_DIM / 4;
    const int n_user4 = NUM_USERS * EMB_DIM / 4;

    lgcn_init<<<(n_tot4 + 255) / 256, 256, 0, stream>>>(
        (const float4*)user_emb, (const float4*)item_emb,
        embA, (float4*)acc, n_user4, n_tot4);

    // row_ptr build
    hipMemsetAsync(deg, 0, NN * sizeof(int), stream);
    lgcn_hist<<<(nnz + 255) / 256, 256, 0, stream>>>(rows, deg, nnz);
    const int nScanBlocks = (NN + SCAN_CHUNK - 1) / SCAN_CHUNK;   // 74
    lgcn_scan1<<<nScanBlocks, 256, 0, stream>>>(deg, row_ptr, bsums, NN);
    lgcn_scan2<<<1, 256, 0, stream>>>(bsums, nScanBlocks);
    lgcn_scan3<<<(NN + 255) / 256, 256, 0, stream>>>(row_ptr, bsums, gcur, NN, nnz);

    // two-level counting sort into exact CSR
    lgcn_binA<<<(nnz + EPB - 1) / EPB, 256, 0, stream>>>(rows, cols, vals, gcur,
                                                         cv_tmp, nnz);
    lgcn_binB<<<NBKT, 256, 0, stream>>>(row_ptr, cv_tmp, cv);

    // 3 layers of gather SpMM (ping-pong embA/embB), acc fused
    const int spmm_blocks = (NN * 64 + 255) / 256;   // one wave per row
    uint2* ein = embA; uint2* eout = embB;
    for (int layer = 0; layer < 3; ++layer) {
        lgcn_spmm<<<spmm_blocks, 256, 0, stream>>>(row_ptr, cv, ein, eout,
                                                   (float4*)acc);
        uint2* tmp = ein; ein = eout; eout = tmp;
    }

    lgcn_dot<<<(BATCH * 16 + 255) / 256, 256, 0, stream>>>(
        acc, user_idx, item_idx, out, BATCH);
}

// Round 8
// 741.308 us; speedup vs baseline: 9.4340x; 1.2154x over previous
//
#include <hip/hip_runtime.h>
#include <hip/hip_fp16.h>

#define NUM_USERS 100000
#define NUM_ITEMS 50000
#define NN (NUM_USERS + NUM_ITEMS)
#define EMB_DIM 64
#define BATCH 16384
#define RPB 128                       // rows per coarse bucket
#define NBKT ((NN + RPB - 1) / RPB)   // 1172 buckets
#define EPB 16384                     // edges per binA block
#define SLOT 5120                     // cv_tmp slot per bucket (mean 4096, +16 sigma)

// init: acc = concat(user_emb, item_emb) fp32; emb = same, quantized fp16
__global__ void lgcn_init(const float4* __restrict__ user_emb,
                          const float4* __restrict__ item_emb,
                          uint2* __restrict__ embh, float4* __restrict__ acc,
                          int n_user4, int n_tot4) {
    int i = blockIdx.x * blockDim.x + threadIdx.x;
    if (i >= n_tot4) return;
    float4 v = (i < n_user4) ? user_emb[i] : item_emb[i - n_user4];
    acc[i] = v;
    __half2 lo = __float22half2_rn(make_float2(v.x, v.y));
    __half2 hi = __float22half2_rn(make_float2(v.z, v.w));
    uint2 o;
    o.x = *(unsigned int*)&lo;
    o.y = *(unsigned int*)&hi;
    embh[i] = o;
}

// seed per-bucket slot cursors
__global__ void lgcn_seed(int* __restrict__ gcur) {
    int i = blockIdx.x * blockDim.x + threadIdx.x;
    if (i < NBKT) gcur[i] = i * SLOT;
}

// binA: coarse bucket scatter with block-aggregated claims into fixed slots.
// Packs {row_local<<18 | col, val_bits}.
__global__ void __launch_bounds__(256) lgcn_binA(
        const int* __restrict__ rows, const int* __restrict__ cols,
        const float* __restrict__ vals, int* __restrict__ gcur,
        int2* __restrict__ cv_tmp, int nnz) {
    __shared__ int hist[NBKT];
    __shared__ int cur[NBKT];
    int t = threadIdx.x;
    int base = blockIdx.x * EPB;
    for (int i = t; i < NBKT; i += 256) hist[i] = 0;
    __syncthreads();
    for (int i = base + t; i < base + EPB && i < nnz; i += 256)
        atomicAdd(&hist[rows[i] >> 7], 1);
    __syncthreads();
    for (int b = t; b < NBKT; b += 256) {
        int c = hist[b];
        cur[b] = c ? atomicAdd(&gcur[b], c) : 0;
    }
    __syncthreads();
    for (int i = base + t; i < base + EPB && i < nnz; i += 256) {
        int r = rows[i];
        int p = atomicAdd(&cur[r >> 7], 1);
        cv_tmp[p] = make_int2(((r & (RPB - 1)) << 18) | cols[i],
                              __float_as_int(vals[i]));
    }
}

// bscan: exclusive scan of bucket counts (gcur[b]-b*SLOT) -> bptr
__global__ void lgcn_bscan(const int* __restrict__ gcur, int* __restrict__ bptr,
                           int* __restrict__ row_ptr, int nnz) {
    __shared__ int lds[NBKT];
    int t = threadIdx.x;
    for (int i = t; i < NBKT; i += 256) lds[i] = gcur[i] - i * SLOT;
    __syncthreads();
    if (t == 0) {
        int run = 0;
        for (int i = 0; i < NBKT; ++i) { int c = lds[i]; lds[i] = run; run += c; }
    }
    __syncthreads();
    for (int i = t; i < NBKT; i += 256) bptr[i] = lds[i];
    if (t == 0) { bptr[NBKT] = nnz; row_ptr[NN] = nnz; }
}

// binB: one workgroup per bucket. LDS-histogram the 128 row-locals from the
// bucket's slot window, 128-wide LDS scan -> writes row_ptr for its rows,
// then scatters into exact CSR (all writes in a contiguous ~32KB window).
__global__ void __launch_bounds__(256) lgcn_binB(
        const int* __restrict__ gcur, const int* __restrict__ bptr,
        const int2* __restrict__ cv_tmp, int2* __restrict__ cv,
        int* __restrict__ row_ptr) {
    __shared__ int hist[RPB];
    __shared__ int pfx[RPB];
    __shared__ int cur[RPB];
    int b = blockIdx.x;
    int t = threadIdx.x;
    int slot = b * SLOT;
    int cnt  = gcur[b] - slot;
    int base = bptr[b];
    int r0 = b * RPB;
    int nrows = NN - r0; if (nrows > RPB) nrows = RPB;

    if (t < RPB) hist[t] = 0;
    __syncthreads();
    for (int i = t; i < cnt; i += 256)
        atomicAdd(&hist[((unsigned)cv_tmp[slot + i].x) >> 18], 1);
    __syncthreads();
    // inclusive Hillis-Steele over 128, then exclusive = incl - own
    if (t < RPB) pfx[t] = hist[t];
    __syncthreads();
    for (int off = 1; off < RPB; off <<= 1) {
        int x = 0;
        if (t < RPB && t >= off) x = pfx[t - off];
        __syncthreads();
        if (t < RPB) pfx[t] += x;
        __syncthreads();
    }
    if (t < RPB) {
        int excl = base + pfx[t] - hist[t];
        cur[t] = excl;
        if (t < nrows) row_ptr[r0 + t] = excl;
    }
    __syncthreads();
    for (int i = t; i < cnt; i += 256) {
        int2 p = cv_tmp[slot + i];
        int rl = ((unsigned)p.x) >> 18;
        int pos = atomicAdd(&cur[rl], 1);
        cv[pos] = make_int2(p.x & 0x3FFFF, p.y);
    }
}

// ---- gather SpMM, fp16 table: one wave per row; 4 groups x 16 dim-lanes.
// Each lane gathers 8B (4 halves) of emb[col]; k-loop unrolled x8 for MLP.
// nxt(fp16)[r] = sum_e val*emb[col]; acc(fp32)[r] += same (fused, fp32 regs)
__global__ void __launch_bounds__(256) lgcn_spmm(
        const int* __restrict__ row_ptr,
        const int2* __restrict__ cv,
        const uint2* __restrict__ embh,
        uint2* __restrict__ nxth,
        float4* __restrict__ acc4) {
    int wid = (blockIdx.x * blockDim.x + threadIdx.x) >> 6;
    int lane = threadIdx.x & 63;
    if (wid >= NN) return;
    int start = row_ptr[wid];
    int n = row_ptr[wid + 1] - start;
    int grp  = lane >> 4;    // 0..3 edge group
    int dim4 = lane & 15;    // 8B (4-half) slice of the 64-dim row
    const int2* ep = cv + start;

    float4 a = {0.f, 0.f, 0.f, 0.f};
    int m = n >> 2;          // rounds where all 4 groups have an edge
    int k = 0;
    for (; k + 8 <= m; k += 8) {
        int2 p[8];
        uint2 raw[8];
#pragma unroll
        for (int j = 0; j < 8; ++j) p[j] = ep[4 * (k + j) + grp];
#pragma unroll
        for (int j = 0; j < 8; ++j)
            raw[j] = embh[(long long)p[j].x * 16 + dim4];
#pragma unroll
        for (int j = 0; j < 8; ++j) {
            float v = __int_as_float(p[j].y);
            __half2* h = (__half2*)&raw[j];
            float2 f0 = __half22float2(h[0]);
            float2 f1 = __half22float2(h[1]);
            a.x += v * f0.x; a.y += v * f0.y;
            a.z += v * f1.x; a.w += v * f1.y;
        }
    }
    for (; k < m; ++k) {
        int2 p = ep[4 * k + grp];
        uint2 raw = embh[(long long)p.x * 16 + dim4];
        float v = __int_as_float(p.y);
        __half2* h = (__half2*)&raw;
        float2 f0 = __half22float2(h[0]);
        float2 f1 = __half22float2(h[1]);
        a.x += v * f0.x; a.y += v * f0.y;
        a.z += v * f1.x; a.w += v * f1.y;
    }
    int rem = n & 3;
    if (grp < rem) {
        int2 p = ep[4 * m + grp];
        uint2 raw = embh[(long long)p.x * 16 + dim4];
        float v = __int_as_float(p.y);
        __half2* h = (__half2*)&raw;
        float2 f0 = __half22float2(h[0]);
        float2 f1 = __half22float2(h[1]);
        a.x += v * f0.x; a.y += v * f0.y;
        a.z += v * f1.x; a.w += v * f1.y;
    }

    // reduce the 4 edge-groups onto group 0
    a.x += __shfl_xor(a.x, 16); a.y += __shfl_xor(a.y, 16);
    a.z += __shfl_xor(a.z, 16); a.w += __shfl_xor(a.w, 16);
    a.x += __shfl_xor(a.x, 32); a.y += __shfl_xor(a.y, 32);
    a.z += __shfl_xor(a.z, 32); a.w += __shfl_xor(a.w, 32);
    if (grp == 0) {
        long long o = (long long)wid * 16 + dim4;
        float4 av = acc4[o];
        __half2 lo = __float22half2_rn(make_float2(a.x, a.y));
        __half2 hi = __float22half2_rn(make_float2(a.z, a.w));
        uint2 ov;
        ov.x = *(unsigned int*)&lo;
        ov.y = *(unsigned int*)&hi;
        nxth[o] = ov;
        av.x += a.x; av.y += a.y; av.z += a.z; av.w += a.w;
        acc4[o] = av;
    }
}

// out[b] = dot(acc[u], acc[NUM_USERS+i]) / 16 ; 16 lanes per output
__global__ void lgcn_dot(const float* __restrict__ acc,
                         const int* __restrict__ user_idx,
                         const int* __restrict__ item_idx,
                         float* __restrict__ out, int batch) {
    int t = blockIdx.x * blockDim.x + threadIdx.x;
    int b = t >> 4;
    if (b >= batch) return;
    int l = t & 15;
    int u = user_idx[b];
    int it = item_idx[b];
    const float4* ue = (const float4*)(acc + (long long)u * EMB_DIM);
    const float4* ie = (const float4*)(acc + (long long)(NUM_USERS + it) * EMB_DIM);
    float4 a = ue[l], c = ie[l];
    float s = a.x * c.x + a.y * c.y + a.z * c.z + a.w * c.w;
    s += __shfl_down(s, 8, 16);
    s += __shfl_down(s, 4, 16);
    s += __shfl_down(s, 2, 16);
    s += __shfl_down(s, 1, 16);
    if (l == 0) out[b] = s * (1.0f / 16.0f);
}

extern "C" void kernel_launch(void* const* d_in, const int* in_sizes, int n_in,
                              void* d_out, int out_size, void* d_ws, size_t ws_size,
                              hipStream_t stream) {
    const float* user_emb = (const float*)d_in[0];
    const float* item_emb = (const float*)d_in[1];
    const int*   rows     = (const int*)d_in[2];
    const int*   cols     = (const int*)d_in[3];
    const float* vals     = (const float*)d_in[4];
    const int*   user_idx = (const int*)d_in[5];
    const int*   item_idx = (const int*)d_in[6];
    float* out = (float*)d_out;

    const int nnz = in_sizes[2];
    const size_t node_floats = (size_t)NN * EMB_DIM;      // 9.6M
    const size_t node_uint2  = node_floats / 4;           // 2.4M (fp16 rows)

    // workspace: acc fp32 (38.4MB) | embA (19.2) | embB (19.2) | cv (38.4)
    //            | cv_tmp slotted (NBKT*SLOT*8 = 48MB) | small ints
    float* acc     = (float*)d_ws;
    uint2* embA    = (uint2*)(acc + node_floats);
    uint2* embB    = embA + node_uint2;
    int2*  cv      = (int2*)(embB + node_uint2);
    int2*  cv_tmp  = cv + nnz;
    int*   gcur    = (int*)(cv_tmp + (size_t)NBKT * SLOT);
    int*   bptr    = gcur + NBKT;                         // NBKT+1
    int*   row_ptr = bptr + NBKT + 1;                     // NN+1

    const int n_tot4  = NN * EMB_DIM / 4;
    const int n_user4 = NUM_USERS * EMB_DIM / 4;

    lgcn_init<<<(n_tot4 + 255) / 256, 256, 0, stream>>>(
        (const float4*)user_emb, (const float4*)item_emb,
        embA, (float4*)acc, n_user4, n_tot4);

    // slotted two-level counting sort into exact CSR (row_ptr built in binB)
    lgcn_seed<<<(NBKT + 255) / 256, 256, 0, stream>>>(gcur);
    lgcn_binA<<<(nnz + EPB - 1) / EPB, 256, 0, stream>>>(rows, cols, vals, gcur,
                                                         cv_tmp, nnz);
    lgcn_bscan<<<1, 256, 0, stream>>>(gcur, bptr, row_ptr, nnz);
    lgcn_binB<<<NBKT, 256, 0, stream>>>(gcur, bptr, cv_tmp, cv, row_ptr);

    // 3 layers of gather SpMM (ping-pong embA/embB), acc fused
    const int spmm_blocks = (NN * 64 + 255) / 256;   // one wave per row
    uint2* ein = embA; uint2* eout = embB;
    for (int layer = 0; layer < 3; ++layer) {
        lgcn_spmm<<<spmm_blocks, 256, 0, stream>>>(row_ptr, cv, ein, eout,
                                                   (float4*)acc);
        uint2* tmp = ein; ein = eout; eout = tmp;
    }

    lgcn_dot<<<(BATCH * 16 + 255) / 256, 256, 0, stream>>>(
        acc, user_idx, item_idx, out, BATCH);
}

// Round 9
// 603.685 us; speedup vs baseline: 11.5846x; 1.2280x over previous
//
#include <hip/hip_runtime.h>
#include <hip/hip_fp16.h>

#define NUM_USERS 100000
#define NUM_ITEMS 50000
#define NN (NUM_USERS + NUM_ITEMS)
#define EMB_DIM 64
#define BATCH 16384
#define RPB 128                       // rows per coarse bucket
#define NBKT ((NN + RPB - 1) / RPB)   // 1172 buckets
#define EPB 16384                     // edges per binA block
#define SLOT 5120                     // cv_tmp slot per bucket (mean 4096, +16 sigma)

// init: acc = concat(user_emb, item_emb) fp32; emb = same, quantized fp16
__global__ void lgcn_init(const float4* __restrict__ user_emb,
                          const float4* __restrict__ item_emb,
                          uint2* __restrict__ embh, float4* __restrict__ acc,
                          int n_user4, int n_tot4) {
    int i = blockIdx.x * blockDim.x + threadIdx.x;
    if (i >= n_tot4) return;
    float4 v = (i < n_user4) ? user_emb[i] : item_emb[i - n_user4];
    acc[i] = v;
    __half2 lo = __float22half2_rn(make_float2(v.x, v.y));
    __half2 hi = __float22half2_rn(make_float2(v.z, v.w));
    uint2 o;
    o.x = *(unsigned int*)&lo;
    o.y = *(unsigned int*)&hi;
    embh[i] = o;
}

// seed per-bucket slot cursors
__global__ void lgcn_seed(int* __restrict__ gcur) {
    int i = blockIdx.x * blockDim.x + threadIdx.x;
    if (i < NBKT) gcur[i] = i * SLOT;
}

// binA: coarse bucket scatter with block-aggregated claims into fixed slots.
// 1024 threads (16 waves) so 293 blocks still give ~4.6 waves/SIMD.
// Packs {row_local<<18 | col, val_bits}.
__global__ void __launch_bounds__(1024) lgcn_binA(
        const int* __restrict__ rows, const int* __restrict__ cols,
        const float* __restrict__ vals, int* __restrict__ gcur,
        int2* __restrict__ cv_tmp, int nnz) {
    __shared__ int hist[NBKT];
    __shared__ int cur[NBKT];
    int t = threadIdx.x;
    int base = blockIdx.x * EPB;
    for (int i = t; i < NBKT; i += 1024) hist[i] = 0;
    __syncthreads();
    for (int i = base + t; i < base + EPB && i < nnz; i += 1024)
        atomicAdd(&hist[rows[i] >> 7], 1);
    __syncthreads();
    for (int b = t; b < NBKT; b += 1024) {
        int c = hist[b];
        cur[b] = c ? atomicAdd(&gcur[b], c) : 0;
    }
    __syncthreads();
    for (int i = base + t; i < base + EPB && i < nnz; i += 1024) {
        int r = rows[i];
        int p = atomicAdd(&cur[r >> 7], 1);
        cv_tmp[p] = make_int2(((r & (RPB - 1)) << 18) | cols[i],
                              __float_as_int(vals[i]));
    }
}

// bscan: exclusive scan of bucket counts (gcur[b]-b*SLOT) -> bptr
__global__ void lgcn_bscan(const int* __restrict__ gcur, int* __restrict__ bptr,
                           int* __restrict__ row_ptr, int nnz) {
    __shared__ int lds[NBKT];
    int t = threadIdx.x;
    for (int i = t; i < NBKT; i += 256) lds[i] = gcur[i] - i * SLOT;
    __syncthreads();
    if (t == 0) {
        int run = 0;
        for (int i = 0; i < NBKT; ++i) { int c = lds[i]; lds[i] = run; run += c; }
    }
    __syncthreads();
    for (int i = t; i < NBKT; i += 256) bptr[i] = lds[i];
    if (t == 0) { bptr[NBKT] = nnz; row_ptr[NN] = nnz; }
}

// binB: one workgroup per bucket, 512 threads. LDS-histogram the 128
// row-locals, 128-wide LDS scan -> writes row_ptr, scatter into exact CSR.
__global__ void __launch_bounds__(512) lgcn_binB(
        const int* __restrict__ gcur, const int* __restrict__ bptr,
        const int2* __restrict__ cv_tmp, int2* __restrict__ cv,
        int* __restrict__ row_ptr) {
    __shared__ int hist[RPB];
    __shared__ int pfx[RPB];
    __shared__ int cur[RPB];
    int b = blockIdx.x;
    int t = threadIdx.x;
    int slot = b * SLOT;
    int cnt  = gcur[b] - slot;
    int base = bptr[b];
    int r0 = b * RPB;
    int nrows = NN - r0; if (nrows > RPB) nrows = RPB;

    if (t < RPB) hist[t] = 0;
    __syncthreads();
    for (int i = t; i < cnt; i += 512)
        atomicAdd(&hist[((unsigned)cv_tmp[slot + i].x) >> 18], 1);
    __syncthreads();
    if (t < RPB) pfx[t] = hist[t];
    __syncthreads();
    for (int off = 1; off < RPB; off <<= 1) {
        int x = 0;
        if (t < RPB && t >= off) x = pfx[t - off];
        __syncthreads();
        if (t < RPB) pfx[t] += x;
        __syncthreads();
    }
    if (t < RPB) {
        int excl = base + pfx[t] - hist[t];
        cur[t] = excl;
        if (t < nrows) row_ptr[r0 + t] = excl;
    }
    __syncthreads();
    for (int i = t; i < cnt; i += 512) {
        int2 p = cv_tmp[slot + i];
        int rl = ((unsigned)p.x) >> 18;
        int pos = atomicAdd(&cur[rl], 1);
        cv[pos] = make_int2(p.x & 0x3FFFF, p.y);
    }
}

// ---- gather SpMM, fp16 table: one wave per row; 8 edge-groups x 8 lanes.
// Lane owns a 16B (8-half) slice of the 64-dim row; x4 unroll => 32 edges
// in flight per wave. nxt(fp16) = sum val*emb[col]; acc(fp32) += same.
__global__ void __launch_bounds__(256) lgcn_spmm(
        const int* __restrict__ row_ptr,
        const int2* __restrict__ cv,
        const uint4* __restrict__ embh,
        uint4* __restrict__ nxth,
        float4* __restrict__ acc4) {
    int wid = (blockIdx.x * blockDim.x + threadIdx.x) >> 6;
    int lane = threadIdx.x & 63;
    if (wid >= NN) return;
    int start = row_ptr[wid];
    int n = row_ptr[wid + 1] - start;
    int grp  = lane >> 3;    // 0..7 edge group
    int dim8 = lane & 7;     // 16B (8-half) slice index
    const int2* ep = cv + start;

    float4 a0 = {0.f, 0.f, 0.f, 0.f};
    float4 a1 = {0.f, 0.f, 0.f, 0.f};
    int m = n >> 3;          // rounds where all 8 groups have an edge
    int k = 0;
    for (; k + 4 <= m; k += 4) {
        int2 p[4]; uint4 raw[4];
#pragma unroll
        for (int j = 0; j < 4; ++j) p[j] = ep[8 * (k + j) + grp];
#pragma unroll
        for (int j = 0; j < 4; ++j)
            raw[j] = embh[(long long)p[j].x * 8 + dim8];
#pragma unroll
        for (int j = 0; j < 4; ++j) {
            float v = __int_as_float(p[j].y);
            __half2* h = (__half2*)&raw[j];
            float2 f0 = __half22float2(h[0]);
            float2 f1 = __half22float2(h[1]);
            float2 f2 = __half22float2(h[2]);
            float2 f3 = __half22float2(h[3]);
            a0.x += v * f0.x; a0.y += v * f0.y;
            a0.z += v * f1.x; a0.w += v * f1.y;
            a1.x += v * f2.x; a1.y += v * f2.y;
            a1.z += v * f3.x; a1.w += v * f3.y;
        }
    }
    for (; k < m; ++k) {
        int2 p = ep[8 * k + grp];
        uint4 raw = embh[(long long)p.x * 8 + dim8];
        float v = __int_as_float(p.y);
        __half2* h = (__half2*)&raw;
        float2 f0 = __half22float2(h[0]);
        float2 f1 = __half22float2(h[1]);
        float2 f2 = __half22float2(h[2]);
        float2 f3 = __half22float2(h[3]);
        a0.x += v * f0.x; a0.y += v * f0.y;
        a0.z += v * f1.x; a0.w += v * f1.y;
        a1.x += v * f2.x; a1.y += v * f2.y;
        a1.z += v * f3.x; a1.w += v * f3.y;
    }
    int rem = n & 7;
    if (grp < rem) {
        int2 p = ep[8 * m + grp];
        uint4 raw = embh[(long long)p.x * 8 + dim8];
        float v = __int_as_float(p.y);
        __half2* h = (__half2*)&raw;
        float2 f0 = __half22float2(h[0]);
        float2 f1 = __half22float2(h[1]);
        float2 f2 = __half22float2(h[2]);
        float2 f3 = __half22float2(h[3]);
        a0.x += v * f0.x; a0.y += v * f0.y;
        a0.z += v * f1.x; a0.w += v * f1.y;
        a1.x += v * f2.x; a1.y += v * f2.y;
        a1.z += v * f3.x; a1.w += v * f3.y;
    }

    // reduce the 8 edge-groups onto group 0 (lanes 0..7)
#pragma unroll
    for (int off = 8; off < 64; off <<= 1) {
        a0.x += __shfl_xor(a0.x, off); a0.y += __shfl_xor(a0.y, off);
        a0.z += __shfl_xor(a0.z, off); a0.w += __shfl_xor(a0.w, off);
        a1.x += __shfl_xor(a1.x, off); a1.y += __shfl_xor(a1.y, off);
        a1.z += __shfl_xor(a1.z, off); a1.w += __shfl_xor(a1.w, off);
    }
    if (grp == 0) {
        long long o = (long long)wid * 8 + dim8;
        __half2 h0 = __float22half2_rn(make_float2(a0.x, a0.y));
        __half2 h1 = __float22half2_rn(make_float2(a0.z, a0.w));
        __half2 h2 = __float22half2_rn(make_float2(a1.x, a1.y));
        __half2 h3 = __float22half2_rn(make_float2(a1.z, a1.w));
        uint4 ov;
        ov.x = *(unsigned int*)&h0; ov.y = *(unsigned int*)&h1;
        ov.z = *(unsigned int*)&h2; ov.w = *(unsigned int*)&h3;
        nxth[o] = ov;
        long long oa = (long long)wid * 16 + dim8 * 2;
        float4 av0 = acc4[oa], av1 = acc4[oa + 1];
        av0.x += a0.x; av0.y += a0.y; av0.z += a0.z; av0.w += a0.w;
        av1.x += a1.x; av1.y += a1.y; av1.z += a1.z; av1.w += a1.w;
        acc4[oa] = av0; acc4[oa + 1] = av1;
    }
}

// out[b] = dot(acc[u], acc[NUM_USERS+i]) / 16 ; 16 lanes per output
__global__ void lgcn_dot(const float* __restrict__ acc,
                         const int* __restrict__ user_idx,
                         const int* __restrict__ item_idx,
                         float* __restrict__ out, int batch) {
    int t = blockIdx.x * blockDim.x + threadIdx.x;
    int b = t >> 4;
    if (b >= batch) return;
    int l = t & 15;
    int u = user_idx[b];
    int it = item_idx[b];
    const float4* ue = (const float4*)(acc + (long long)u * EMB_DIM);
    const float4* ie = (const float4*)(acc + (long long)(NUM_USERS + it) * EMB_DIM);
    float4 a = ue[l], c = ie[l];
    float s = a.x * c.x + a.y * c.y + a.z * c.z + a.w * c.w;
    s += __shfl_down(s, 8, 16);
    s += __shfl_down(s, 4, 16);
    s += __shfl_down(s, 2, 16);
    s += __shfl_down(s, 1, 16);
    if (l == 0) out[b] = s * (1.0f / 16.0f);
}

extern "C" void kernel_launch(void* const* d_in, const int* in_sizes, int n_in,
                              void* d_out, int out_size, void* d_ws, size_t ws_size,
                              hipStream_t stream) {
    const float* user_emb = (const float*)d_in[0];
    const float* item_emb = (const float*)d_in[1];
    const int*   rows     = (const int*)d_in[2];
    const int*   cols     = (const int*)d_in[3];
    const float* vals     = (const float*)d_in[4];
    const int*   user_idx = (const int*)d_in[5];
    const int*   item_idx = (const int*)d_in[6];
    float* out = (float*)d_out;

    const int nnz = in_sizes[2];
    const size_t node_floats = (size_t)NN * EMB_DIM;      // 9.6M
    const size_t node_uint2  = node_floats / 4;           // 2.4M (fp16 rows)

    // workspace: acc fp32 (38.4MB) | embA (19.2) | embB (19.2) | cv (38.4)
    //            | cv_tmp slotted (NBKT*SLOT*8 = 48MB) | small ints
    float* acc     = (float*)d_ws;
    uint2* embA    = (uint2*)(acc + node_floats);
    uint2* embB    = embA + node_uint2;
    int2*  cv      = (int2*)(embB + node_uint2);
    int2*  cv_tmp  = cv + nnz;
    int*   gcur    = (int*)(cv_tmp + (size_t)NBKT * SLOT);
    int*   bptr    = gcur + NBKT;                         // NBKT+1
    int*   row_ptr = bptr + NBKT + 1;                     // NN+1

    const int n_tot4  = NN * EMB_DIM / 4;
    const int n_user4 = NUM_USERS * EMB_DIM / 4;

    lgcn_init<<<(n_tot4 + 255) / 256, 256, 0, stream>>>(
        (const float4*)user_emb, (const float4*)item_emb,
        embA, (float4*)acc, n_user4, n_tot4);

    // slotted two-level counting sort into exact CSR (row_ptr built in binB)
    lgcn_seed<<<(NBKT + 255) / 256, 256, 0, stream>>>(gcur);
    lgcn_binA<<<(nnz + EPB - 1) / EPB, 1024, 0, stream>>>(rows, cols, vals, gcur,
                                                          cv_tmp, nnz);
    lgcn_bscan<<<1, 256, 0, stream>>>(gcur, bptr, row_ptr, nnz);
    lgcn_binB<<<NBKT, 512, 0, stream>>>(gcur, bptr, cv_tmp, cv, row_ptr);

    // 3 layers of gather SpMM (ping-pong embA/embB), acc fused
    const int spmm_blocks = (NN * 64 + 255) / 256;   // one wave per row
    uint2* ein = embA; uint2* eout = embB;
    for (int layer = 0; layer < 3; ++layer) {
        lgcn_spmm<<<spmm_blocks, 256, 0, stream>>>(row_ptr, cv,
                                                   (const uint4*)ein,
                                                   (uint4*)eout, (float4*)acc);
        uint2* tmp = ein; ein = eout; eout = tmp;
    }

    lgcn_dot<<<(BATCH * 16 + 255) / 256, 256, 0, stream>>>(
        acc, user_idx, item_idx, out, BATCH);
}

// Round 10
// 572.115 us; speedup vs baseline: 12.2239x; 1.0552x over previous
//
#include <hip/hip_runtime.h>
#include <hip/hip_fp16.h>

#define NUM_USERS 100000
#define NUM_ITEMS 50000
#define NN (NUM_USERS + NUM_ITEMS)
#define EMB_DIM 64
#define BATCH 16384
#define RPB 256                       // rows per coarse bucket
#define NBKT ((NN + RPB - 1) / RPB)   // 586 buckets
#define SLOT 9216                     // cv_tmp slot per bucket (mean 8192, +11 sigma)
#define NBLKA 256                     // binA blocks == CU count (no tail)

// init: acc = concat(user_emb, item_emb) fp32; emb = same, quantized fp16
__global__ void lgcn_init(const float4* __restrict__ user_emb,
                          const float4* __restrict__ item_emb,
                          uint2* __restrict__ embh, float4* __restrict__ acc,
                          int n_user4, int n_tot4) {
    int i = blockIdx.x * blockDim.x + threadIdx.x;
    if (i >= n_tot4) return;
    float4 v = (i < n_user4) ? user_emb[i] : item_emb[i - n_user4];
    acc[i] = v;
    __half2 lo = __float22half2_rn(make_float2(v.x, v.y));
    __half2 hi = __float22half2_rn(make_float2(v.z, v.w));
    uint2 o;
    o.x = *(unsigned int*)&lo;
    o.y = *(unsigned int*)&hi;
    embh[i] = o;
}

// seed per-bucket slot cursors
__global__ void lgcn_seed(int* __restrict__ gcur) {
    int i = blockIdx.x * blockDim.x + threadIdx.x;
    if (i < NBKT) gcur[i] = i * SLOT;
}

// binA: coarse bucket scatter, block-aggregated claims into fixed slots.
// 256 blocks x 1024 threads; runs of ~32 edges (256B = 4 lines) per
// (block,bucket) -> low boundary-line sharing.
// Packs {row_local<<18 | col, val_bits}.
__global__ void __launch_bounds__(1024) lgcn_binA(
        const int* __restrict__ rows, const int* __restrict__ cols,
        const float* __restrict__ vals, int* __restrict__ gcur,
        int2* __restrict__ cv_tmp, int nnz, int epb) {
    __shared__ int hist[NBKT];
    __shared__ int cur[NBKT];
    int t = threadIdx.x;
    int base = blockIdx.x * epb;
    int end  = base + epb; if (end > nnz) end = nnz;
    for (int i = t; i < NBKT; i += 1024) hist[i] = 0;
    __syncthreads();
    for (int i = base + t; i < end; i += 1024)
        atomicAdd(&hist[rows[i] >> 8], 1);
    __syncthreads();
    for (int b = t; b < NBKT; b += 1024) {
        int c = hist[b];
        cur[b] = c ? atomicAdd(&gcur[b], c) : 0;
    }
    __syncthreads();
    for (int i = base + t; i < end; i += 1024) {
        int r = rows[i];
        int p = atomicAdd(&cur[r >> 8], 1);
        cv_tmp[p] = make_int2(((r & (RPB - 1)) << 18) | cols[i],
                              __float_as_int(vals[i]));
    }
}

// bscan: exclusive scan of bucket counts (gcur[b]-b*SLOT) -> bptr
__global__ void lgcn_bscan(const int* __restrict__ gcur, int* __restrict__ bptr,
                           int* __restrict__ row_ptr, int nnz) {
    __shared__ int lds[NBKT];
    int t = threadIdx.x;
    for (int i = t; i < NBKT; i += 256) lds[i] = gcur[i] - i * SLOT;
    __syncthreads();
    if (t == 0) {
        int run = 0;
        for (int i = 0; i < NBKT; ++i) { int c = lds[i]; lds[i] = run; run += c; }
    }
    __syncthreads();
    for (int i = t; i < NBKT; i += 256) bptr[i] = lds[i];
    if (t == 0) { bptr[NBKT] = nnz; row_ptr[NN] = nnz; }
}

// binB: one workgroup per bucket, 512 threads. LDS-histogram the 256
// row-locals, 256-wide LDS scan -> writes row_ptr, scatter into exact CSR
// (writes stay in the bucket's contiguous ~64KB window).
__global__ void __launch_bounds__(512) lgcn_binB(
        const int* __restrict__ gcur, const int* __restrict__ bptr,
        const int2* __restrict__ cv_tmp, int2* __restrict__ cv,
        int* __restrict__ row_ptr) {
    __shared__ int hist[RPB];
    __shared__ int pfx[RPB];
    __shared__ int cur[RPB];
    int b = blockIdx.x;
    int t = threadIdx.x;
    int slot = b * SLOT;
    int cnt  = gcur[b] - slot;
    int base = bptr[b];
    int r0 = b * RPB;
    int nrows = NN - r0; if (nrows > RPB) nrows = RPB;

    if (t < RPB) hist[t] = 0;
    __syncthreads();
    for (int i = t; i < cnt; i += 512)
        atomicAdd(&hist[((unsigned)cv_tmp[slot + i].x) >> 18], 1);
    __syncthreads();
    if (t < RPB) pfx[t] = hist[t];
    __syncthreads();
    for (int off = 1; off < RPB; off <<= 1) {
        int x = 0;
        if (t < RPB && t >= off) x = pfx[t - off];
        __syncthreads();
        if (t < RPB) pfx[t] += x;
        __syncthreads();
    }
    if (t < RPB) {
        int excl = base + pfx[t] - hist[t];
        cur[t] = excl;
        if (t < nrows) row_ptr[r0 + t] = excl;
    }
    __syncthreads();
    for (int i = t; i < cnt; i += 512) {
        int2 p = cv_tmp[slot + i];
        int rl = ((unsigned)p.x) >> 18;
        int pos = atomicAdd(&cur[rl], 1);
        cv[pos] = make_int2(p.x & 0x3FFFF, p.y);
    }
}

// ---- gather SpMM, fp16 table: one wave per row; 8 edge-groups x 8 lanes.
// Lane owns a 16B (8-half) slice of the 64-dim row; x4 unroll => 32 edges
// in flight per wave. nxt(fp16) = sum val*emb[col] (skipped on last layer);
// acc(fp32) += same (fused).
__global__ void __launch_bounds__(256) lgcn_spmm(
        const int* __restrict__ row_ptr,
        const int2* __restrict__ cv,
        const uint4* __restrict__ embh,
        uint4* __restrict__ nxth,
        float4* __restrict__ acc4,
        int write_nxt) {
    int wid = (blockIdx.x * blockDim.x + threadIdx.x) >> 6;
    int lane = threadIdx.x & 63;
    if (wid >= NN) return;
    int start = row_ptr[wid];
    int n = row_ptr[wid + 1] - start;
    int grp  = lane >> 3;    // 0..7 edge group
    int dim8 = lane & 7;     // 16B (8-half) slice index
    const int2* ep = cv + start;

    float4 a0 = {0.f, 0.f, 0.f, 0.f};
    float4 a1 = {0.f, 0.f, 0.f, 0.f};
    int m = n >> 3;          // rounds where all 8 groups have an edge
    int k = 0;
    for (; k + 4 <= m; k += 4) {
        int2 p[4]; uint4 raw[4];
#pragma unroll
        for (int j = 0; j < 4; ++j) p[j] = ep[8 * (k + j) + grp];
#pragma unroll
        for (int j = 0; j < 4; ++j)
            raw[j] = embh[(long long)p[j].x * 8 + dim8];
#pragma unroll
        for (int j = 0; j < 4; ++j) {
            float v = __int_as_float(p[j].y);
            __half2* h = (__half2*)&raw[j];
            float2 f0 = __half22float2(h[0]);
            float2 f1 = __half22float2(h[1]);
            float2 f2 = __half22float2(h[2]);
            float2 f3 = __half22float2(h[3]);
            a0.x += v * f0.x; a0.y += v * f0.y;
            a0.z += v * f1.x; a0.w += v * f1.y;
            a1.x += v * f2.x; a1.y += v * f2.y;
            a1.z += v * f3.x; a1.w += v * f3.y;
        }
    }
    for (; k < m; ++k) {
        int2 p = ep[8 * k + grp];
        uint4 raw = embh[(long long)p.x * 8 + dim8];
        float v = __int_as_float(p.y);
        __half2* h = (__half2*)&raw;
        float2 f0 = __half22float2(h[0]);
        float2 f1 = __half22float2(h[1]);
        float2 f2 = __half22float2(h[2]);
        float2 f3 = __half22float2(h[3]);
        a0.x += v * f0.x; a0.y += v * f0.y;
        a0.z += v * f1.x; a0.w += v * f1.y;
        a1.x += v * f2.x; a1.y += v * f2.y;
        a1.z += v * f3.x; a1.w += v * f3.y;
    }
    int rem = n & 7;
    if (grp < rem) {
        int2 p = ep[8 * m + grp];
        uint4 raw = embh[(long long)p.x * 8 + dim8];
        float v = __int_as_float(p.y);
        __half2* h = (__half2*)&raw;
        float2 f0 = __half22float2(h[0]);
        float2 f1 = __half22float2(h[1]);
        float2 f2 = __half22float2(h[2]);
        float2 f3 = __half22float2(h[3]);
        a0.x += v * f0.x; a0.y += v * f0.y;
        a0.z += v * f1.x; a0.w += v * f1.y;
        a1.x += v * f2.x; a1.y += v * f2.y;
        a1.z += v * f3.x; a1.w += v * f3.y;
    }

    // reduce the 8 edge-groups onto group 0 (lanes 0..7)
#pragma unroll
    for (int off = 8; off < 64; off <<= 1) {
        a0.x += __shfl_xor(a0.x, off); a0.y += __shfl_xor(a0.y, off);
        a0.z += __shfl_xor(a0.z, off); a0.w += __shfl_xor(a0.w, off);
        a1.x += __shfl_xor(a1.x, off); a1.y += __shfl_xor(a1.y, off);
        a1.z += __shfl_xor(a1.z, off); a1.w += __shfl_xor(a1.w, off);
    }
    if (grp == 0) {
        if (write_nxt) {
            long long o = (long long)wid * 8 + dim8;
            __half2 h0 = __float22half2_rn(make_float2(a0.x, a0.y));
            __half2 h1 = __float22half2_rn(make_float2(a0.z, a0.w));
            __half2 h2 = __float22half2_rn(make_float2(a1.x, a1.y));
            __half2 h3 = __float22half2_rn(make_float2(a1.z, a1.w));
            uint4 ov;
            ov.x = *(unsigned int*)&h0; ov.y = *(unsigned int*)&h1;
            ov.z = *(unsigned int*)&h2; ov.w = *(unsigned int*)&h3;
            nxth[o] = ov;
        }
        long long oa = (long long)wid * 16 + dim8 * 2;
        float4 av0 = acc4[oa], av1 = acc4[oa + 1];
        av0.x += a0.x; av0.y += a0.y; av0.z += a0.z; av0.w += a0.w;
        av1.x += a1.x; av1.y += a1.y; av1.z += a1.z; av1.w += a1.w;
        acc4[oa] = av0; acc4[oa + 1] = av1;
    }
}

// out[b] = dot(acc[u], acc[NUM_USERS+i]) / 16 ; 16 lanes per output
__global__ void lgcn_dot(const float* __restrict__ acc,
                         const int* __restrict__ user_idx,
                         const int* __restrict__ item_idx,
                         float* __restrict__ out, int batch) {
    int t = blockIdx.x * blockDim.x + threadIdx.x;
    int b = t >> 4;
    if (b >= batch) return;
    int l = t & 15;
    int u = user_idx[b];
    int it = item_idx[b];
    const float4* ue = (const float4*)(acc + (long long)u * EMB_DIM);
    const float4* ie = (const float4*)(acc + (long long)(NUM_USERS + it) * EMB_DIM);
    float4 a = ue[l], c = ie[l];
    float s = a.x * c.x + a.y * c.y + a.z * c.z + a.w * c.w;
    s += __shfl_down(s, 8, 16);
    s += __shfl_down(s, 4, 16);
    s += __shfl_down(s, 2, 16);
    s += __shfl_down(s, 1, 16);
    if (l == 0) out[b] = s * (1.0f / 16.0f);
}

extern "C" void kernel_launch(void* const* d_in, const int* in_sizes, int n_in,
                              void* d_out, int out_size, void* d_ws, size_t ws_size,
                              hipStream_t stream) {
    const float* user_emb = (const float*)d_in[0];
    const float* item_emb = (const float*)d_in[1];
    const int*   rows     = (const int*)d_in[2];
    const int*   cols     = (const int*)d_in[3];
    const float* vals     = (const float*)d_in[4];
    const int*   user_idx = (const int*)d_in[5];
    const int*   item_idx = (const int*)d_in[6];
    float* out = (float*)d_out;

    const int nnz = in_sizes[2];
    const size_t node_floats = (size_t)NN * EMB_DIM;      // 9.6M
    const size_t node_uint2  = node_floats / 4;           // 2.4M (fp16 rows)

    // workspace: acc fp32 (38.4MB) | embA (19.2) | embB (19.2) | cv (38.4)
    //            | cv_tmp slotted (NBKT*SLOT*8 = 43.2MB) | small ints
    float* acc     = (float*)d_ws;
    uint2* embA    = (uint2*)(acc + node_floats);
    uint2* embB    = embA + node_uint2;
    int2*  cv      = (int2*)(embB + node_uint2);
    int2*  cv_tmp  = cv + nnz;
    int*   gcur    = (int*)(cv_tmp + (size_t)NBKT * SLOT);
    int*   bptr    = gcur + NBKT;                         // NBKT+1
    int*   row_ptr = bptr + NBKT + 1;                     // NN+1

    const int n_tot4  = NN * EMB_DIM / 4;
    const int n_user4 = NUM_USERS * EMB_DIM / 4;
    const int epb = (nnz + NBLKA - 1) / NBLKA;            // 18750

    lgcn_init<<<(n_tot4 + 255) / 256, 256, 0, stream>>>(
        (const float4*)user_emb, (const float4*)item_emb,
        embA, (float4*)acc, n_user4, n_tot4);

    // slotted two-level counting sort into exact CSR (row_ptr built in binB)
    lgcn_seed<<<(NBKT + 255) / 256, 256, 0, stream>>>(gcur);
    lgcn_binA<<<NBLKA, 1024, 0, stream>>>(rows, cols, vals, gcur, cv_tmp, nnz, epb);
    lgcn_bscan<<<1, 256, 0, stream>>>(gcur, bptr, row_ptr, nnz);
    lgcn_binB<<<NBKT, 512, 0, stream>>>(gcur, bptr, cv_tmp, cv, row_ptr);

    // 3 layers of gather SpMM (ping-pong embA/embB), acc fused
    const int spmm_blocks = (NN * 64 + 255) / 256;   // one wave per row
    uint2* ein = embA; uint2* eout = embB;
    for (int layer = 0; layer < 3; ++layer) {
        lgcn_spmm<<<spmm_blocks, 256, 0, stream>>>(row_ptr, cv,
                                                   (const uint4*)ein,
                                                   (uint4*)eout, (float4*)acc,
                                                   layer < 2 ? 1 : 0);
        uint2* tmp = ein; ein = eout; eout = tmp;
    }

    lgcn_dot<<<(BATCH * 16 + 255) / 256, 256, 0, stream>>>(
        acc, user_idx, item_idx, out, BATCH);
}

// Round 11
// 541.487 us; speedup vs baseline: 12.9153x; 1.0566x over previous
//
#include <hip/hip_runtime.h>
#include <hip/hip_fp16.h>

#define NUM_USERS 100000
#define NUM_ITEMS 50000
#define NN (NUM_USERS + NUM_ITEMS)
#define EMB_DIM 64
#define BATCH 16384
#define RPB 256                       // rows per coarse bucket
#define NBKT ((NN + RPB - 1) / RPB)   // 586 buckets
#define SLOT 10240                    // cv_tmp slot per bucket (mean 8192 + holes)
#define NBLKA 256                     // binA blocks == CU count (no tail)
#define SENT (1 << 26)                // sentinel flag for binA hole entries

// init: E0 = concat(user_emb, item_emb) quantized fp16
__global__ void lgcn_init(const float4* __restrict__ user_emb,
                          const float4* __restrict__ item_emb,
                          uint2* __restrict__ embh, int n_user4, int n_tot4) {
    int i = blockIdx.x * blockDim.x + threadIdx.x;
    if (i >= n_tot4) return;
    float4 v = (i < n_user4) ? user_emb[i] : item_emb[i - n_user4];
    __half2 lo = __float22half2_rn(make_float2(v.x, v.y));
    __half2 hi = __float22half2_rn(make_float2(v.z, v.w));
    uint2 o;
    o.x = *(unsigned int*)&lo;
    o.y = *(unsigned int*)&hi;
    embh[i] = o;
}

// seed per-bucket slot cursors and real counts
__global__ void lgcn_seed(int* __restrict__ gcur, int* __restrict__ gcnt) {
    int i = blockIdx.x * blockDim.x + threadIdx.x;
    if (i < NBKT) { gcur[i] = i * SLOT; gcnt[i] = 0; }
}

// binA: coarse bucket scatter, block-aggregated claims into fixed slots.
// Claims are padded to multiples of 8 edges (64B) so no two blocks share a
// cache line in cv_tmp (write amp -> 1.0); holes carry SENT and are skipped
// by binB. Real counts accumulate in gcnt. Packs {row_local<<18|col, val}.
__global__ void __launch_bounds__(1024) lgcn_binA(
        const int* __restrict__ rows, const int* __restrict__ cols,
        const float* __restrict__ vals, int* __restrict__ gcur,
        int* __restrict__ gcnt, int2* __restrict__ cv_tmp, int nnz, int epb) {
    __shared__ int hist[NBKT];
    __shared__ int cur[NBKT];
    __shared__ int cbase[NBKT];
    int t = threadIdx.x;
    int base = blockIdx.x * epb;
    int end  = base + epb; if (end > nnz) end = nnz;
    for (int i = t; i < NBKT; i += 1024) hist[i] = 0;
    __syncthreads();
    for (int i = base + t; i < end; i += 1024)
        atomicAdd(&hist[rows[i] >> 8], 1);
    __syncthreads();
    for (int b = t; b < NBKT; b += 1024) {
        int c = hist[b];
        int p = 0;
        if (c) {
            int cp = (c + 7) & ~7;               // line-align the claim
            p = atomicAdd(&gcur[b], cp);
            atomicAdd(&gcnt[b], c);
        }
        cur[b] = p; cbase[b] = p;
    }
    __syncthreads();
    for (int i = base + t; i < end; i += 1024) {
        int r = rows[i];
        int p = atomicAdd(&cur[r >> 8], 1);
        cv_tmp[p] = make_int2(((r & (RPB - 1)) << 18) | cols[i],
                              __float_as_int(vals[i]));
    }
    __syncthreads();
    // sentinel-fill the padding holes (lines already owned by this block)
    for (int b = t; b < NBKT; b += 1024) {
        int c = hist[b];
        if (c) {
            int cp = (c + 7) & ~7;
            for (int j = cbase[b] + c; j < cbase[b] + cp; ++j)
                cv_tmp[j] = make_int2(SENT, 0);
        }
    }
}

// bscan: exclusive scan of real bucket counts -> bptr
__global__ void lgcn_bscan(const int* __restrict__ gcnt, int* __restrict__ bptr,
                           int* __restrict__ row_ptr, int nnz) {
    __shared__ int lds[NBKT];
    int t = threadIdx.x;
    for (int i = t; i < NBKT; i += 256) lds[i] = gcnt[i];
    __syncthreads();
    if (t == 0) {
        int run = 0;
        for (int i = 0; i < NBKT; ++i) { int c = lds[i]; lds[i] = run; run += c; }
    }
    __syncthreads();
    for (int i = t; i < NBKT; i += 256) bptr[i] = lds[i];
    if (t == 0) { bptr[NBKT] = nnz; row_ptr[NN] = nnz; }
}

// binB: one workgroup per bucket, 512 threads. LDS-histogram the 256
// row-locals (skipping sentinels), 256-wide LDS scan -> writes row_ptr,
// scatter into exact CSR (writes stay in the bucket's contiguous window).
__global__ void __launch_bounds__(512) lgcn_binB(
        const int* __restrict__ gcur, const int* __restrict__ bptr,
        const int2* __restrict__ cv_tmp, int2* __restrict__ cv,
        int* __restrict__ row_ptr) {
    __shared__ int hist[RPB];
    __shared__ int pfx[RPB];
    __shared__ int cur[RPB];
    int b = blockIdx.x;
    int t = threadIdx.x;
    int slot = b * SLOT;
    int wcnt = gcur[b] - slot;          // window length incl. holes
    int base = bptr[b];
    int r0 = b * RPB;
    int nrows = NN - r0; if (nrows > RPB) nrows = RPB;

    if (t < RPB) hist[t] = 0;
    __syncthreads();
    for (int i = t; i < wcnt; i += 512) {
        int x = cv_tmp[slot + i].x;
        if (!(x & SENT)) atomicAdd(&hist[((unsigned)x) >> 18], 1);
    }
    __syncthreads();
    if (t < RPB) pfx[t] = hist[t];
    __syncthreads();
    for (int off = 1; off < RPB; off <<= 1) {
        int x = 0;
        if (t < RPB && t >= off) x = pfx[t - off];
        __syncthreads();
        if (t < RPB) pfx[t] += x;
        __syncthreads();
    }
    if (t < RPB) {
        int excl = base + pfx[t] - hist[t];
        cur[t] = excl;
        if (t < nrows) row_ptr[r0 + t] = excl;
    }
    __syncthreads();
    for (int i = t; i < wcnt; i += 512) {
        int2 p = cv_tmp[slot + i];
        if (p.x & SENT) continue;
        int rl = ((unsigned)p.x) >> 18;
        int pos = atomicAdd(&cur[rl], 1);
        cv[pos] = make_int2(p.x & 0x3FFFF, p.y);
    }
}

// ---- gather SpMM, fp16 tables: one wave per row; 8 edge-groups x 8 lanes.
// Lane owns a 16B (8-half) slice; x4 unroll => 32 edges in flight per wave.
// Eout(fp16)[r] = sum_e val * Ein[col]. No fp32 acc (layer sum deferred to dot).
__global__ void __launch_bounds__(256) lgcn_spmm(
        const int* __restrict__ row_ptr,
        const int2* __restrict__ cv,
        const uint4* __restrict__ embh,
        uint4* __restrict__ nxth) {
    int wid = (blockIdx.x * blockDim.x + threadIdx.x) >> 6;
    int lane = threadIdx.x & 63;
    if (wid >= NN) return;
    int start = row_ptr[wid];
    int n = row_ptr[wid + 1] - start;
    int grp  = lane >> 3;    // 0..7 edge group
    int dim8 = lane & 7;     // 16B (8-half) slice index
    const int2* ep = cv + start;

    float4 a0 = {0.f, 0.f, 0.f, 0.f};
    float4 a1 = {0.f, 0.f, 0.f, 0.f};
    int m = n >> 3;          // rounds where all 8 groups have an edge
    int k = 0;
    for (; k + 4 <= m; k += 4) {
        int2 p[4]; uint4 raw[4];
#pragma unroll
        for (int j = 0; j < 4; ++j) p[j] = ep[8 * (k + j) + grp];
#pragma unroll
        for (int j = 0; j < 4; ++j)
            raw[j] = embh[(long long)p[j].x * 8 + dim8];
#pragma unroll
        for (int j = 0; j < 4; ++j) {
            float v = __int_as_float(p[j].y);
            __half2* h = (__half2*)&raw[j];
            float2 f0 = __half22float2(h[0]);
            float2 f1 = __half22float2(h[1]);
            float2 f2 = __half22float2(h[2]);
            float2 f3 = __half22float2(h[3]);
            a0.x += v * f0.x; a0.y += v * f0.y;
            a0.z += v * f1.x; a0.w += v * f1.y;
            a1.x += v * f2.x; a1.y += v * f2.y;
            a1.z += v * f3.x; a1.w += v * f3.y;
        }
    }
    for (; k < m; ++k) {
        int2 p = ep[8 * k + grp];
        uint4 raw = embh[(long long)p.x * 8 + dim8];
        float v = __int_as_float(p.y);
        __half2* h = (__half2*)&raw;
        float2 f0 = __half22float2(h[0]);
        float2 f1 = __half22float2(h[1]);
        float2 f2 = __half22float2(h[2]);
        float2 f3 = __half22float2(h[3]);
        a0.x += v * f0.x; a0.y += v * f0.y;
        a0.z += v * f1.x; a0.w += v * f1.y;
        a1.x += v * f2.x; a1.y += v * f2.y;
        a1.z += v * f3.x; a1.w += v * f3.y;
    }
    int rem = n & 7;
    if (grp < rem) {
        int2 p = ep[8 * m + grp];
        uint4 raw = embh[(long long)p.x * 8 + dim8];
        float v = __int_as_float(p.y);
        __half2* h = (__half2*)&raw;
        float2 f0 = __half22float2(h[0]);
        float2 f1 = __half22float2(h[1]);
        float2 f2 = __half22float2(h[2]);
        float2 f3 = __half22float2(h[3]);
        a0.x += v * f0.x; a0.y += v * f0.y;
        a0.z += v * f1.x; a0.w += v * f1.y;
        a1.x += v * f2.x; a1.y += v * f2.y;
        a1.z += v * f3.x; a1.w += v * f3.y;
    }

    // reduce the 8 edge-groups onto group 0 (lanes 0..7)
#pragma unroll
    for (int off = 8; off < 64; off <<= 1) {
        a0.x += __shfl_xor(a0.x, off); a0.y += __shfl_xor(a0.y, off);
        a0.z += __shfl_xor(a0.z, off); a0.w += __shfl_xor(a0.w, off);
        a1.x += __shfl_xor(a1.x, off); a1.y += __shfl_xor(a1.y, off);
        a1.z += __shfl_xor(a1.z, off); a1.w += __shfl_xor(a1.w, off);
    }
    if (grp == 0) {
        long long o = (long long)wid * 8 + dim8;
        __half2 h0 = __float22half2_rn(make_float2(a0.x, a0.y));
        __half2 h1 = __float22half2_rn(make_float2(a0.z, a0.w));
        __half2 h2 = __float22half2_rn(make_float2(a1.x, a1.y));
        __half2 h3 = __float22half2_rn(make_float2(a1.z, a1.w));
        uint4 ov;
        ov.x = *(unsigned int*)&h0; ov.y = *(unsigned int*)&h1;
        ov.z = *(unsigned int*)&h2; ov.w = *(unsigned int*)&h3;
        nxth[o] = ov;
    }
}

// out[b] = dot(sum_l E_l[u], sum_l E_l[NUM_USERS+i]) / 16 ; 16 lanes/output.
// Layer-sum is computed here in fp32 from the 4 fp16 tables.
__global__ void lgcn_dot(const uint2* __restrict__ E0, const uint2* __restrict__ E1,
                         const uint2* __restrict__ E2, const uint2* __restrict__ E3,
                         const int* __restrict__ user_idx,
                         const int* __restrict__ item_idx,
                         float* __restrict__ out, int batch) {
    int t = blockIdx.x * blockDim.x + threadIdx.x;
    int b = t >> 4;
    if (b >= batch) return;
    int l = t & 15;
    long long ru = (long long)user_idx[b] * 16 + l;
    long long ri = (long long)(NUM_USERS + item_idx[b]) * 16 + l;
    float4 su = {0.f, 0.f, 0.f, 0.f};
    float4 si = {0.f, 0.f, 0.f, 0.f};
    const uint2* Es[4] = {E0, E1, E2, E3};
#pragma unroll
    for (int q = 0; q < 4; ++q) {
        uint2 a = Es[q][ru];
        uint2 c = Es[q][ri];
        __half2* ha = (__half2*)&a;
        __half2* hc = (__half2*)&c;
        float2 a0 = __half22float2(ha[0]), a1 = __half22float2(ha[1]);
        float2 c0 = __half22float2(hc[0]), c1 = __half22float2(hc[1]);
        su.x += a0.x; su.y += a0.y; su.z += a1.x; su.w += a1.y;
        si.x += c0.x; si.y += c0.y; si.z += c1.x; si.w += c1.y;
    }
    float s = su.x * si.x + su.y * si.y + su.z * si.z + su.w * si.w;
    s += __shfl_down(s, 8, 16);
    s += __shfl_down(s, 4, 16);
    s += __shfl_down(s, 2, 16);
    s += __shfl_down(s, 1, 16);
    if (l == 0) out[b] = s * (1.0f / 16.0f);
}

extern "C" void kernel_launch(void* const* d_in, const int* in_sizes, int n_in,
                              void* d_out, int out_size, void* d_ws, size_t ws_size,
                              hipStream_t stream) {
    const float* user_emb = (const float*)d_in[0];
    const float* item_emb = (const float*)d_in[1];
    const int*   rows     = (const int*)d_in[2];
    const int*   cols     = (const int*)d_in[3];
    const float* vals     = (const float*)d_in[4];
    const int*   user_idx = (const int*)d_in[5];
    const int*   item_idx = (const int*)d_in[6];
    float* out = (float*)d_out;

    const int nnz = in_sizes[2];
    const size_t node_uint2 = (size_t)NN * 16;            // 2.4M uint2 per table

    // workspace: E0..E3 fp16 (4 x 19.2MB) | cv (38.4) | cv_tmp (46.9) | ints
    uint2* E[4];
    E[0] = (uint2*)d_ws;
    E[1] = E[0] + node_uint2;
    E[2] = E[1] + node_uint2;
    E[3] = E[2] + node_uint2;
    int2*  cv      = (int2*)(E[3] + node_uint2);
    int2*  cv_tmp  = cv + nnz;
    int*   gcur    = (int*)(cv_tmp + (size_t)NBKT * SLOT);
    int*   gcnt    = gcur + NBKT;
    int*   bptr    = gcnt + NBKT;                         // NBKT+1
    int*   row_ptr = bptr + NBKT + 1;                     // NN+1

    const int n_tot4  = NN * EMB_DIM / 4;
    const int n_user4 = NUM_USERS * EMB_DIM / 4;
    const int epb = (nnz + NBLKA - 1) / NBLKA;            // 18750

    lgcn_init<<<(n_tot4 + 255) / 256, 256, 0, stream>>>(
        (const float4*)user_emb, (const float4*)item_emb,
        E[0], n_user4, n_tot4);

    // slotted two-level counting sort into exact CSR (row_ptr built in binB)
    lgcn_seed<<<(NBKT + 255) / 256, 256, 0, stream>>>(gcur, gcnt);
    lgcn_binA<<<NBLKA, 1024, 0, stream>>>(rows, cols, vals, gcur, gcnt,
                                          cv_tmp, nnz, epb);
    lgcn_bscan<<<1, 256, 0, stream>>>(gcnt, bptr, row_ptr, nnz);
    lgcn_binB<<<NBKT, 512, 0, stream>>>(gcur, bptr, cv_tmp, cv, row_ptr);

    // 3 layers of gather SpMM: E0 -> E1 -> E2 -> E3
    const int spmm_blocks = (NN * 64 + 255) / 256;   // one wave per row
    for (int layer = 0; layer < 3; ++layer) {
        lgcn_spmm<<<spmm_blocks, 256, 0, stream>>>(row_ptr, cv,
                                                   (const uint4*)E[layer],
                                                   (uint4*)E[layer + 1]);
    }

    lgcn_dot<<<(BATCH * 16 + 255) / 256, 256, 0, stream>>>(
        E[0], E[1], E[2], E[3], user_idx, item_idx, out, BATCH);
}

// Round 12
// 530.552 us; speedup vs baseline: 13.1815x; 1.0206x over previous
//
#include <hip/hip_runtime.h>
#include <hip/hip_fp16.h>

#define NUM_USERS 100000
#define NUM_ITEMS 50000
#define NN (NUM_USERS + NUM_ITEMS)
#define EMB_DIM 64
#define BATCH 16384
#define RPA 512                       // rows per super-bucket (binA staging)
#define NBA ((NN + RPA - 1) / RPA)    // 293 super-buckets
#define RPB 256                       // rows per fine bucket (CSR/binB)
#define NBB ((NN + RPB - 1) / RPB)    // 586 fine buckets
#define SLOT 20480                    // cv_tmp slot per super-bucket (mean 16384)
#define NBLKA 512                     // binA blocks (2/CU at 61KB LDS)
#define SDEPTH 24                     // staging depth per bucket
#define SENT (1 << 27)                // sentinel flag for padding holes

// init: E0 = concat(user_emb, item_emb) quantized fp16
__global__ void lgcn_init(const float4* __restrict__ user_emb,
                          const float4* __restrict__ item_emb,
                          uint2* __restrict__ embh, int n_user4, int n_tot4) {
    int i = blockIdx.x * blockDim.x + threadIdx.x;
    if (i >= n_tot4) return;
    float4 v = (i < n_user4) ? user_emb[i] : item_emb[i - n_user4];
    __half2 lo = __float22half2_rn(make_float2(v.x, v.y));
    __half2 hi = __float22half2_rn(make_float2(v.z, v.w));
    uint2 o;
    o.x = *(unsigned int*)&lo;
    o.y = *(unsigned int*)&hi;
    embh[i] = o;
}

// seed packed per-super-bucket state: low32 = slot cursor, high32 = count
__global__ void lgcn_seed(unsigned long long* __restrict__ gq) {
    int i = blockIdx.x * blockDim.x + threadIdx.x;
    if (i < NBA) gq[i] = (unsigned long long)(unsigned)(i * SLOT);
}

// binA: super-bucket scatter with LDS write-combining. Each bucket's stream
// is staged in a 24-deep LDS ring; after each 512-edge round, owner threads
// flush complete 8-entry (64B) chunks as aligned int4 stores -> each cv_tmp
// line is written once, fully, within one round (no partial-line evictions).
// Packs {row_local9<<18 | col, val_bits}; claims padded to 8 w/ SENT holes.
__global__ void __launch_bounds__(512) lgcn_binA(
        const int* __restrict__ rows, const int* __restrict__ cols,
        const float* __restrict__ vals, unsigned long long* __restrict__ gq,
        int2* __restrict__ cv_tmp, int nnz, int epb) {
    __shared__ int2 stage[NBA][SDEPTH];   // 56.3 KB
    __shared__ int hist[NBA];
    __shared__ int gbase[NBA];
    __shared__ int scnt[NBA];
    __shared__ int flushed[NBA];
    int t = threadIdx.x;
    int base = blockIdx.x * epb;
    int end  = base + epb; if (end > nnz) end = nnz;
    if (t < NBA) { hist[t] = 0; scnt[t] = 0; flushed[t] = 0; }
    __syncthreads();
    for (int i = base + t; i < end; i += 512)
        atomicAdd(&hist[rows[i] >> 9], 1);
    __syncthreads();
    if (t < NBA) {
        int c = hist[t];
        int p = 0;
        if (c) {
            int cp = (c + 7) & ~7;       // line-align the claim
            unsigned long long old = atomicAdd(&gq[t],
                ((unsigned long long)c << 32) | (unsigned)cp);
            p = (int)(unsigned)old;
        }
        gbase[t] = p;
    }
    __syncthreads();
    for (int r0 = base; r0 < end; r0 += 512) {
        int i = r0 + t;
        if (i < end) {
            int r = rows[i];
            int b = r >> 9;
            int k = atomicAdd(&scnt[b], 1);
            stage[b][k % SDEPTH] = make_int2(((r & 511) << 18) | cols[i],
                                             __float_as_int(vals[i]));
        }
        __syncthreads();
        if (t < NBA) {
            int s = flushed[t], c = scnt[t];
            int gb = gbase[t];
            while (c - s >= 8) {
                int4* dst = (int4*)&cv_tmp[gb + s];   // 16B-aligned (s,gb mult of 8)
#pragma unroll
                for (int j = 0; j < 8; j += 2) {
                    int2 e0 = stage[t][(s + j) % SDEPTH];
                    int2 e1 = stage[t][(s + j + 1) % SDEPTH];
                    dst[j >> 1] = make_int4(e0.x, e0.y, e1.x, e1.y);
                }
                s += 8;
            }
            flushed[t] = s;
        }
        __syncthreads();
    }
    // drain remainder (<8) + sentinel-pad to the claimed 8-boundary
    if (t < NBA) {
        int s = flushed[t], c = scnt[t];
        int cp = (c + 7) & ~7;
        int gb = gbase[t];
        for (int j = s; j < c; ++j) cv_tmp[gb + j] = stage[t][j % SDEPTH];
        for (int j = c; j < cp; ++j) cv_tmp[gb + j] = make_int2(SENT, 0);
    }
}

// bscan: exclusive scan of super-bucket counts (gq high words) -> bptr
__global__ void lgcn_bscan(const unsigned long long* __restrict__ gq,
                           int* __restrict__ bptr, int* __restrict__ row_ptr,
                           int nnz) {
    __shared__ int lds[NBA];
    int t = threadIdx.x;
    if (t < NBA) lds[t] = (int)(gq[t] >> 32);
    __syncthreads();
    if (t == 0) {
        int run = 0;
        for (int i = 0; i < NBA; ++i) { int c = lds[i]; lds[i] = run; run += c; }
    }
    __syncthreads();
    if (t < NBA) bptr[t] = lds[t];
    if (t == 0) { bptr[NBA] = nnz; row_ptr[NN] = nnz; }
}

// binB: one workgroup per FINE bucket (256 rows). Scans its super-bucket's
// window filtering on parity bit (rl bit 8); LDS-hist + 256-scan -> row_ptr,
// then scatter into exact CSR (contiguous ~64KB write window).
__global__ void __launch_bounds__(512) lgcn_binB(
        const unsigned long long* __restrict__ gq, const int* __restrict__ bptr,
        const int2* __restrict__ cv_tmp, int2* __restrict__ cv,
        int* __restrict__ row_ptr) {
    __shared__ int hist[RPB];
    __shared__ int pfx[RPB];
    __shared__ int cur[RPB];
    __shared__ int mybase;
    int j = blockIdx.x;
    int s = j >> 1;
    int par = j & 1;
    int t = threadIdx.x;
    long long w0 = (long long)s * SLOT;
    unsigned long long q = gq[s];
    int wlen = (int)(unsigned)q - s * SLOT;   // window length incl. holes
    int stot = (int)(q >> 32);                // real edges in super-bucket
    int r0 = j * RPB;
    int nrows = NN - r0; if (nrows > RPB) nrows = RPB;

    if (t < RPB) hist[t] = 0;
    __syncthreads();
    for (int i = t; i < wlen; i += 512) {
        int x = cv_tmp[w0 + i].x;
        if (!(x & SENT) && (((x >> 26) & 1) == par))
            atomicAdd(&hist[(x >> 18) & 255], 1);
    }
    __syncthreads();
    if (t < RPB) pfx[t] = hist[t];
    __syncthreads();
    for (int off = 1; off < RPB; off <<= 1) {
        int x = 0;
        if (t < RPB && t >= off) x = pfx[t - off];
        __syncthreads();
        if (t < RPB) pfx[t] += x;
        __syncthreads();
    }
    if (t == 0) {
        int myt = pfx[RPB - 1];
        mybase = bptr[s] + (par ? (stot - myt) : 0);
    }
    __syncthreads();
    if (t < RPB) {
        int excl = mybase + pfx[t] - hist[t];
        cur[t] = excl;
        if (t < nrows) row_ptr[r0 + t] = excl;
    }
    __syncthreads();
    for (int i = t; i < wlen; i += 512) {
        int2 p = cv_tmp[w0 + i];
        int x = p.x;
        if ((x & SENT) || (((x >> 26) & 1) != par)) continue;
        int rl = (x >> 18) & 255;
        int pos = atomicAdd(&cur[rl], 1);
        cv[pos] = make_int2(x & 0x3FFFF, p.y);
    }
}

// ---- gather SpMM, fp16 tables: one wave per row; 8 edge-groups x 8 lanes.
// Lane owns a 16B (8-half) slice; x4 unroll => 32 edges in flight per wave.
// Eout(fp16)[r] = sum_e val * Ein[col].
__global__ void __launch_bounds__(256) lgcn_spmm(
        const int* __restrict__ row_ptr,
        const int2* __restrict__ cv,
        const uint4* __restrict__ embh,
        uint4* __restrict__ nxth) {
    int wid = (blockIdx.x * blockDim.x + threadIdx.x) >> 6;
    int lane = threadIdx.x & 63;
    if (wid >= NN) return;
    int start = row_ptr[wid];
    int n = row_ptr[wid + 1] - start;
    int grp  = lane >> 3;    // 0..7 edge group
    int dim8 = lane & 7;     // 16B (8-half) slice index
    const int2* ep = cv + start;

    float4 a0 = {0.f, 0.f, 0.f, 0.f};
    float4 a1 = {0.f, 0.f, 0.f, 0.f};
    int m = n >> 3;          // rounds where all 8 groups have an edge
    int k = 0;
    for (; k + 4 <= m; k += 4) {
        int2 p[4]; uint4 raw[4];
#pragma unroll
        for (int j = 0; j < 4; ++j) p[j] = ep[8 * (k + j) + grp];
#pragma unroll
        for (int j = 0; j < 4; ++j)
            raw[j] = embh[(long long)p[j].x * 8 + dim8];
#pragma unroll
        for (int j = 0; j < 4; ++j) {
            float v = __int_as_float(p[j].y);
            __half2* h = (__half2*)&raw[j];
            float2 f0 = __half22float2(h[0]);
            float2 f1 = __half22float2(h[1]);
            float2 f2 = __half22float2(h[2]);
            float2 f3 = __half22float2(h[3]);
            a0.x += v * f0.x; a0.y += v * f0.y;
            a0.z += v * f1.x; a0.w += v * f1.y;
            a1.x += v * f2.x; a1.y += v * f2.y;
            a1.z += v * f3.x; a1.w += v * f3.y;
        }
    }
    for (; k < m; ++k) {
        int2 p = ep[8 * k + grp];
        uint4 raw = embh[(long long)p.x * 8 + dim8];
        float v = __int_as_float(p.y);
        __half2* h = (__half2*)&raw;
        float2 f0 = __half22float2(h[0]);
        float2 f1 = __half22float2(h[1]);
        float2 f2 = __half22float2(h[2]);
        float2 f3 = __half22float2(h[3]);
        a0.x += v * f0.x; a0.y += v * f0.y;
        a0.z += v * f1.x; a0.w += v * f1.y;
        a1.x += v * f2.x; a1.y += v * f2.y;
        a1.z += v * f3.x; a1.w += v * f3.y;
    }
    int rem = n & 7;
    if (grp < rem) {
        int2 p = ep[8 * m + grp];
        uint4 raw = embh[(long long)p.x * 8 + dim8];
        float v = __int_as_float(p.y);
        __half2* h = (__half2*)&raw;
        float2 f0 = __half22float2(h[0]);
        float2 f1 = __half22float2(h[1]);
        float2 f2 = __half22float2(h[2]);
        float2 f3 = __half22float2(h[3]);
        a0.x += v * f0.x; a0.y += v * f0.y;
        a0.z += v * f1.x; a0.w += v * f1.y;
        a1.x += v * f2.x; a1.y += v * f2.y;
        a1.z += v * f3.x; a1.w += v * f3.y;
    }

#pragma unroll
    for (int off = 8; off < 64; off <<= 1) {
        a0.x += __shfl_xor(a0.x, off); a0.y += __shfl_xor(a0.y, off);
        a0.z += __shfl_xor(a0.z, off); a0.w += __shfl_xor(a0.w, off);
        a1.x += __shfl_xor(a1.x, off); a1.y += __shfl_xor(a1.y, off);
        a1.z += __shfl_xor(a1.z, off); a1.w += __shfl_xor(a1.w, off);
    }
    if (grp == 0) {
        long long o = (long long)wid * 8 + dim8;
        __half2 h0 = __float22half2_rn(make_float2(a0.x, a0.y));
        __half2 h1 = __float22half2_rn(make_float2(a0.z, a0.w));
        __half2 h2 = __float22half2_rn(make_float2(a1.x, a1.y));
        __half2 h3 = __float22half2_rn(make_float2(a1.z, a1.w));
        uint4 ov;
        ov.x = *(unsigned int*)&h0; ov.y = *(unsigned int*)&h1;
        ov.z = *(unsigned int*)&h2; ov.w = *(unsigned int*)&h3;
        nxth[o] = ov;
    }
}

// out[b] = dot(sum_l E_l[u], sum_l E_l[NUM_USERS+i]) / 16 ; 16 lanes/output.
__global__ void lgcn_dot(const uint2* __restrict__ E0, const uint2* __restrict__ E1,
                         const uint2* __restrict__ E2, const uint2* __restrict__ E3,
                         const int* __restrict__ user_idx,
                         const int* __restrict__ item_idx,
                         float* __restrict__ out, int batch) {
    int t = blockIdx.x * blockDim.x + threadIdx.x;
    int b = t >> 4;
    if (b >= batch) return;
    int l = t & 15;
    long long ru = (long long)user_idx[b] * 16 + l;
    long long ri = (long long)(NUM_USERS + item_idx[b]) * 16 + l;
    float4 su = {0.f, 0.f, 0.f, 0.f};
    float4 si = {0.f, 0.f, 0.f, 0.f};
    const uint2* Es[4] = {E0, E1, E2, E3};
#pragma unroll
    for (int q = 0; q < 4; ++q) {
        uint2 a = Es[q][ru];
        uint2 c = Es[q][ri];
        __half2* ha = (__half2*)&a;
        __half2* hc = (__half2*)&c;
        float2 a0 = __half22float2(ha[0]), a1 = __half22float2(ha[1]);
        float2 c0 = __half22float2(hc[0]), c1 = __half22float2(hc[1]);
        su.x += a0.x; su.y += a0.y; su.z += a1.x; su.w += a1.y;
        si.x += c0.x; si.y += c0.y; si.z += c1.x; si.w += c1.y;
    }
    float s = su.x * si.x + su.y * si.y + su.z * si.z + su.w * si.w;
    s += __shfl_down(s, 8, 16);
    s += __shfl_down(s, 4, 16);
    s += __shfl_down(s, 2, 16);
    s += __shfl_down(s, 1, 16);
    if (l == 0) out[b] = s * (1.0f / 16.0f);
}

extern "C" void kernel_launch(void* const* d_in, const int* in_sizes, int n_in,
                              void* d_out, int out_size, void* d_ws, size_t ws_size,
                              hipStream_t stream) {
    const float* user_emb = (const float*)d_in[0];
    const float* item_emb = (const float*)d_in[1];
    const int*   rows     = (const int*)d_in[2];
    const int*   cols     = (const int*)d_in[3];
    const float* vals     = (const float*)d_in[4];
    const int*   user_idx = (const int*)d_in[5];
    const int*   item_idx = (const int*)d_in[6];
    float* out = (float*)d_out;

    const int nnz = in_sizes[2];
    const size_t node_uint2 = (size_t)NN * 16;            // 2.4M uint2 per table

    // workspace: E0..E3 fp16 (4 x 19.2MB) | cv (38.4) | cv_tmp (48) | ints
    uint2* E[4];
    E[0] = (uint2*)d_ws;
    E[1] = E[0] + node_uint2;
    E[2] = E[1] + node_uint2;
    E[3] = E[2] + node_uint2;
    int2*  cv      = (int2*)(E[3] + node_uint2);
    int2*  cv_tmp  = cv + nnz;
    unsigned long long* gq = (unsigned long long*)(cv_tmp + (size_t)NBA * SLOT);
    int*   bptr    = (int*)(gq + NBA);                    // NBA+1
    int*   row_ptr = bptr + NBA + 1;                      // NN+1

    const int n_tot4  = NN * EMB_DIM / 4;
    const int n_user4 = NUM_USERS * EMB_DIM / 4;
    const int epb = (nnz + NBLKA - 1) / NBLKA;            // 9375

    lgcn_init<<<(n_tot4 + 255) / 256, 256, 0, stream>>>(
        (const float4*)user_emb, (const float4*)item_emb,
        E[0], n_user4, n_tot4);

    // slotted two-level counting sort into exact CSR (row_ptr built in binB)
    lgcn_seed<<<(NBA + 255) / 256, 256, 0, stream>>>(gq);
    lgcn_binA<<<NBLKA, 512, 0, stream>>>(rows, cols, vals, gq, cv_tmp, nnz, epb);
    lgcn_bscan<<<1, 512, 0, stream>>>(gq, bptr, row_ptr, nnz);
    lgcn_binB<<<NBB, 512, 0, stream>>>(gq, bptr, cv_tmp, cv, row_ptr);

    // 3 layers of gather SpMM: E0 -> E1 -> E2 -> E3
    const int spmm_blocks = (NN * 64 + 255) / 256;   // one wave per row
    for (int layer = 0; layer < 3; ++layer) {
        lgcn_spmm<<<spmm_blocks, 256, 0, stream>>>(row_ptr, cv,
                                                   (const uint4*)E[layer],
                                                   (uint4*)E[layer + 1]);
    }

    lgcn_dot<<<(BATCH * 16 + 255) / 256, 256, 0, stream>>>(
        E[0], E[1], E[2], E[3], user_idx, item_idx, out, BATCH);
}

// Round 13
// 503.362 us; speedup vs baseline: 13.8935x; 1.0540x over previous
//
#include <hip/hip_runtime.h>
#include <hip/hip_fp16.h>

#define NUM_USERS 100000
#define NUM_ITEMS 50000
#define NN (NUM_USERS + NUM_ITEMS)
#define EMB_DIM 64
#define BATCH 16384
#define RPA 512                       // rows per super-bucket (binA staging)
#define NBA ((NN + RPA - 1) / RPA)    // 293 super-buckets
#define RPB 256                       // rows per fine bucket (CSR/binB)
#define NBB ((NN + RPB - 1) / RPB)    // 586 fine buckets
#define SLOT 20480                    // cv_tmp slot per super-bucket (mean 16384)
#define NBLKA 512                     // binA blocks (2/CU at ~58KB LDS)
#define SDEPTH 24                     // staging depth per bucket
#define SENT (1 << 27)                // sentinel flag for padding holes

__device__ __forceinline__ unsigned h2u(__half2 h) {
    union { __half2 h; unsigned u; } x; x.h = h; return x.u;
}
__device__ __forceinline__ __half2 u2h(unsigned u) {
    union { __half2 h; unsigned u; } x; x.u = u; return x.h;
}

// init: E0 = concat(user_emb, item_emb) quantized fp16; also seeds gq and
// row_ptr[NN] (folds the old seed/bscan-tail kernels away).
__global__ void lgcn_init(const float4* __restrict__ user_emb,
                          const float4* __restrict__ item_emb,
                          uint2* __restrict__ embh,
                          unsigned long long* __restrict__ gq,
                          int* __restrict__ row_ptr,
                          int n_user4, int n_tot4, int nnz) {
    int i = blockIdx.x * blockDim.x + threadIdx.x;
    if (i < NBA) gq[i] = (unsigned long long)(unsigned)(i * SLOT);
    if (i == 0) row_ptr[NN] = nnz;
    if (i >= n_tot4) return;
    float4 v = (i < n_user4) ? user_emb[i] : item_emb[i - n_user4];
    __half2 lo = __float22half2_rn(make_float2(v.x, v.y));
    __half2 hi = __float22half2_rn(make_float2(v.z, v.w));
    uint2 o;
    o.x = h2u(lo);
    o.y = h2u(hi);
    embh[i] = o;
}

// binA: super-bucket scatter with LDS write-combining (unchanged from R12).
// Packs {row_local9<<18 | col, val_fp32}; claims padded to 8 w/ SENT holes.
__global__ void __launch_bounds__(512) lgcn_binA(
        const int* __restrict__ rows, const int* __restrict__ cols,
        const float* __restrict__ vals, unsigned long long* __restrict__ gq,
        int2* __restrict__ cv_tmp, int nnz, int epb) {
    __shared__ int2 stage[NBA][SDEPTH];   // 56.3 KB
    __shared__ int hist[NBA];
    __shared__ int gbase[NBA];
    __shared__ int scnt[NBA];
    __shared__ int flushed[NBA];
    int t = threadIdx.x;
    int base = blockIdx.x * epb;
    int end  = base + epb; if (end > nnz) end = nnz;
    if (t < NBA) { hist[t] = 0; scnt[t] = 0; flushed[t] = 0; }
    __syncthreads();
    for (int i = base + t; i < end; i += 512)
        atomicAdd(&hist[rows[i] >> 9], 1);
    __syncthreads();
    if (t < NBA) {
        int c = hist[t];
        int p = 0;
        if (c) {
            int cp = (c + 7) & ~7;       // line-align the claim
            unsigned long long old = atomicAdd(&gq[t],
                ((unsigned long long)c << 32) | (unsigned)cp);
            p = (int)(unsigned)old;
        }
        gbase[t] = p;
    }
    __syncthreads();
    for (int r0 = base; r0 < end; r0 += 512) {
        int i = r0 + t;
        if (i < end) {
            int r = rows[i];
            int b = r >> 9;
            int k = atomicAdd(&scnt[b], 1);
            stage[b][k % SDEPTH] = make_int2(((r & 511) << 18) | cols[i],
                                             __float_as_int(vals[i]));
        }
        __syncthreads();
        if (t < NBA) {
            int s = flushed[t], c = scnt[t];
            int gb = gbase[t];
            while (c - s >= 8) {
                int4* dst = (int4*)&cv_tmp[gb + s];
#pragma unroll
                for (int j = 0; j < 8; j += 2) {
                    int2 e0 = stage[t][(s + j) % SDEPTH];
                    int2 e1 = stage[t][(s + j + 1) % SDEPTH];
                    dst[j >> 1] = make_int4(e0.x, e0.y, e1.x, e1.y);
                }
                s += 8;
            }
            flushed[t] = s;
        }
        __syncthreads();
    }
    if (t < NBA) {
        int s = flushed[t], c = scnt[t];
        int cp = (c + 7) & ~7;
        int gb = gbase[t];
        for (int j = s; j < c; ++j) cv_tmp[gb + j] = stage[t][j % SDEPTH];
        for (int j = c; j < cp; ++j) cv_tmp[gb + j] = make_int2(SENT, 0);
    }
}

// binB: one workgroup per FINE bucket (256 rows). Computes its own global
// base by reducing gq counts (bscan folded in), scans its super-bucket's
// window filtering on parity bit, LDS-hist + scan -> row_ptr, scatters into
// exact CSR with val pre-packed as half2(v,v).
__global__ void __launch_bounds__(512) lgcn_binB(
        const unsigned long long* __restrict__ gq,
        const int2* __restrict__ cv_tmp, int2* __restrict__ cv,
        int* __restrict__ row_ptr) {
    __shared__ int hist[RPB];
    __shared__ int pfx[RPB];
    __shared__ int cur[RPB];
    __shared__ int red[512];
    __shared__ int mybase;
    int j = blockIdx.x;
    int s = j >> 1;
    int par = j & 1;
    int t = threadIdx.x;
    long long w0 = (long long)s * SLOT;
    unsigned long long q = gq[s];
    int wlen = (int)(unsigned)q - s * SLOT;   // window length incl. holes
    int stot = (int)(q >> 32);                // real edges in super-bucket
    int r0 = j * RPB;
    int nrows = NN - r0; if (nrows > RPB) nrows = RPB;

    // bucket base = sum of counts of super-buckets < s (folded bscan)
    int partial = 0;
    for (int i = t; i < NBA; i += 512)
        if (i < s) partial += (int)(gq[i] >> 32);
    red[t] = partial;
    if (t < RPB) hist[t] = 0;
    __syncthreads();
    for (int off = 256; off > 0; off >>= 1) {
        if (t < off) red[t] += red[t + off];
        __syncthreads();
    }
    int base_s = red[0];

    for (int i = t; i < wlen; i += 512) {
        int x = cv_tmp[w0 + i].x;
        if (!(x & SENT) && (((x >> 26) & 1) == par))
            atomicAdd(&hist[(x >> 18) & 255], 1);
    }
    __syncthreads();
    if (t < RPB) pfx[t] = hist[t];
    __syncthreads();
    for (int off = 1; off < RPB; off <<= 1) {
        int x = 0;
        if (t < RPB && t >= off) x = pfx[t - off];
        __syncthreads();
        if (t < RPB) pfx[t] += x;
        __syncthreads();
    }
    if (t == 0) {
        int myt = pfx[RPB - 1];
        mybase = base_s + (par ? (stot - myt) : 0);
    }
    __syncthreads();
    if (t < RPB) {
        int excl = mybase + pfx[t] - hist[t];
        cur[t] = excl;
        if (t < nrows) row_ptr[r0 + t] = excl;
    }
    __syncthreads();
    for (int i = t; i < wlen; i += 512) {
        int2 p = cv_tmp[w0 + i];
        int x = p.x;
        if ((x & SENT) || (((x >> 26) & 1) != par)) continue;
        int rl = (x >> 18) & 255;
        int pos = atomicAdd(&cur[rl], 1);
        __half hv = __float2half(__int_as_float(p.y));
        cv[pos] = make_int2(x & 0x3FFFF, (int)h2u(__half2half2(hv)));
    }
}

// ---- gather SpMM, all-fp16 datapath: one wave per row; 8 edge-groups x 8
// lanes; lane owns 16B (8 halves). Accumulate in __half2 via v_pk_fma_f16
// (val pre-packed as half2(v,v) in cv), reduce in __hadd2, store directly.
__global__ void __launch_bounds__(256) lgcn_spmm(
        const int* __restrict__ row_ptr,
        const int2* __restrict__ cv,
        const uint4* __restrict__ embh,
        uint4* __restrict__ nxth) {
    int wid = (blockIdx.x * blockDim.x + threadIdx.x) >> 6;
    int lane = threadIdx.x & 63;
    if (wid >= NN) return;
    int start = row_ptr[wid];
    int n = row_ptr[wid + 1] - start;
    int grp  = lane >> 3;    // 0..7 edge group
    int dim8 = lane & 7;     // 16B (8-half) slice index
    const int2* ep = cv + start;

    __half2 c0 = __float2half2_rn(0.f);
    __half2 c1 = c0, c2 = c0, c3 = c0;
    int m = n >> 3;          // rounds where all 8 groups have an edge
    int k = 0;
    for (; k + 4 <= m; k += 4) {
        int2 p[4]; uint4 raw[4];
#pragma unroll
        for (int j = 0; j < 4; ++j) p[j] = ep[8 * (k + j) + grp];
#pragma unroll
        for (int j = 0; j < 4; ++j)
            raw[j] = embh[(long long)p[j].x * 8 + dim8];
#pragma unroll
        for (int j = 0; j < 4; ++j) {
            __half2 v2 = u2h((unsigned)p[j].y);
            c0 = __hfma2(v2, u2h(raw[j].x), c0);
            c1 = __hfma2(v2, u2h(raw[j].y), c1);
            c2 = __hfma2(v2, u2h(raw[j].z), c2);
            c3 = __hfma2(v2, u2h(raw[j].w), c3);
        }
    }
    for (; k < m; ++k) {
        int2 p = ep[8 * k + grp];
        uint4 raw = embh[(long long)p.x * 8 + dim8];
        __half2 v2 = u2h((unsigned)p.y);
        c0 = __hfma2(v2, u2h(raw.x), c0);
        c1 = __hfma2(v2, u2h(raw.y), c1);
        c2 = __hfma2(v2, u2h(raw.z), c2);
        c3 = __hfma2(v2, u2h(raw.w), c3);
    }
    int rem = n & 7;
    if (grp < rem) {
        int2 p = ep[8 * m + grp];
        uint4 raw = embh[(long long)p.x * 8 + dim8];
        __half2 v2 = u2h((unsigned)p.y);
        c0 = __hfma2(v2, u2h(raw.x), c0);
        c1 = __hfma2(v2, u2h(raw.y), c1);
        c2 = __hfma2(v2, u2h(raw.z), c2);
        c3 = __hfma2(v2, u2h(raw.w), c3);
    }

    // reduce the 8 edge-groups onto group 0 (lanes 0..7), packed fp16
#pragma unroll
    for (int off = 8; off < 64; off <<= 1) {
        c0 = __hadd2(c0, u2h(__shfl_xor(h2u(c0), off)));
        c1 = __hadd2(c1, u2h(__shfl_xor(h2u(c1), off)));
        c2 = __hadd2(c2, u2h(__shfl_xor(h2u(c2), off)));
        c3 = __hadd2(c3, u2h(__shfl_xor(h2u(c3), off)));
    }
    if (grp == 0) {
        long long o = (long long)wid * 8 + dim8;
        uint4 ov;
        ov.x = h2u(c0); ov.y = h2u(c1); ov.z = h2u(c2); ov.w = h2u(c3);
        nxth[o] = ov;
    }
}

// out[b] = dot(sum_l E_l[u], sum_l E_l[NUM_USERS+i]) / 16 ; 16 lanes/output.
// Layer-sum + dot in fp32.
__global__ void lgcn_dot(const uint2* __restrict__ E0, const uint2* __restrict__ E1,
                         const uint2* __restrict__ E2, const uint2* __restrict__ E3,
                         const int* __restrict__ user_idx,
                         const int* __restrict__ item_idx,
                         float* __restrict__ out, int batch) {
    int t = blockIdx.x * blockDim.x + threadIdx.x;
    int b = t >> 4;
    if (b >= batch) return;
    int l = t & 15;
    long long ru = (long long)user_idx[b] * 16 + l;
    long long ri = (long long)(NUM_USERS + item_idx[b]) * 16 + l;
    float4 su = {0.f, 0.f, 0.f, 0.f};
    float4 si = {0.f, 0.f, 0.f, 0.f};
    const uint2* Es[4] = {E0, E1, E2, E3};
#pragma unroll
    for (int q = 0; q < 4; ++q) {
        uint2 a = Es[q][ru];
        uint2 c = Es[q][ri];
        float2 a0 = __half22float2(u2h(a.x)), a1 = __half22float2(u2h(a.y));
        float2 c0 = __half22float2(u2h(c.x)), c1 = __half22float2(u2h(c.y));
        su.x += a0.x; su.y += a0.y; su.z += a1.x; su.w += a1.y;
        si.x += c0.x; si.y += c0.y; si.z += c1.x; si.w += c1.y;
    }
    float s = su.x * si.x + su.y * si.y + su.z * si.z + su.w * si.w;
    s += __shfl_down(s, 8, 16);
    s += __shfl_down(s, 4, 16);
    s += __shfl_down(s, 2, 16);
    s += __shfl_down(s, 1, 16);
    if (l == 0) out[b] = s * (1.0f / 16.0f);
}

extern "C" void kernel_launch(void* const* d_in, const int* in_sizes, int n_in,
                              void* d_out, int out_size, void* d_ws, size_t ws_size,
                              hipStream_t stream) {
    const float* user_emb = (const float*)d_in[0];
    const float* item_emb = (const float*)d_in[1];
    const int*   rows     = (const int*)d_in[2];
    const int*   cols     = (const int*)d_in[3];
    const float* vals     = (const float*)d_in[4];
    const int*   user_idx = (const int*)d_in[5];
    const int*   item_idx = (const int*)d_in[6];
    float* out = (float*)d_out;

    const int nnz = in_sizes[2];
    const size_t node_uint2 = (size_t)NN * 16;            // 2.4M uint2 per table

    // workspace: E0..E3 fp16 (4 x 19.2MB) | cv (38.4) | cv_tmp (48) | ints
    uint2* E[4];
    E[0] = (uint2*)d_ws;
    E[1] = E[0] + node_uint2;
    E[2] = E[1] + node_uint2;
    E[3] = E[2] + node_uint2;
    int2*  cv      = (int2*)(E[3] + node_uint2);
    int2*  cv_tmp  = cv + nnz;
    unsigned long long* gq = (unsigned long long*)(cv_tmp + (size_t)NBA * SLOT);
    int*   row_ptr = (int*)(gq + NBA);                    // NN+1

    const int n_tot4  = NN * EMB_DIM / 4;
    const int n_user4 = NUM_USERS * EMB_DIM / 4;
    const int epb = (nnz + NBLKA - 1) / NBLKA;            // 9375

    lgcn_init<<<(n_tot4 + 255) / 256, 256, 0, stream>>>(
        (const float4*)user_emb, (const float4*)item_emb,
        E[0], gq, row_ptr, n_user4, n_tot4, nnz);

    lgcn_binA<<<NBLKA, 512, 0, stream>>>(rows, cols, vals, gq, cv_tmp, nnz, epb);
    lgcn_binB<<<NBB, 512, 0, stream>>>(gq, cv_tmp, cv, row_ptr);

    // 3 layers of gather SpMM: E0 -> E1 -> E2 -> E3
    const int spmm_blocks = (NN * 64 + 255) / 256;   // one wave per row
    for (int layer = 0; layer < 3; ++layer) {
        lgcn_spmm<<<spmm_blocks, 256, 0, stream>>>(row_ptr, cv,
                                                   (const uint4*)E[layer],
                                                   (uint4*)E[layer + 1]);
    }

    lgcn_dot<<<(BATCH * 16 + 255) / 256, 256, 0, stream>>>(
        E[0], E[1], E[2], E[3], user_idx, item_idx, out, BATCH);
}